// Round 1
// baseline (1336.042 us; speedup 1.0000x reference)
//
#include <hip/hip_runtime.h>
#include <math.h>

#define N_NODES 100000
#define F_INDIM 256
#define HDIM 32

// ---------------------------------------------------------------------------
// GEMM: XW[N,96] = x[N,256] @ [Wz | Wr | Wh]   (cols 0-31 = z, 32-63 = r, 64-95 = h)
// 32 rows/block, 256 threads: thread = (rowgroup of 4) x (col-in-32), 3 cols apart by 32.
// ---------------------------------------------------------------------------
__global__ __launch_bounds__(256) void gemm_xw(
    const float* __restrict__ x,
    const float* __restrict__ Wz, const float* __restrict__ Wr, const float* __restrict__ Wh,
    float* __restrict__ XW) {
  __shared__ float xs[32][64];     // 8 KB
  __shared__ float wsz[64][32];    // 8 KB
  __shared__ float wsr[64][32];
  __shared__ float wsh[64][32];
  const int t = threadIdx.x;
  const int row0 = blockIdx.x * 32;        // 3125 blocks * 32 = 100000 exactly
  const int cg = t & 31;
  const int rg = (t >> 5) * 4;
  float acc[4][3] = {};
  for (int k0 = 0; k0 < 256; k0 += 64) {
#pragma unroll
    for (int i = 0; i < 8; i++) {          // load x chunk: 32x64
      int l = t + 256 * i;
      int r = l >> 6, kk = l & 63;
      xs[r][kk] = x[(size_t)(row0 + r) * F_INDIM + k0 + kk];
    }
#pragma unroll
    for (int i = 0; i < 8; i++) {          // load W chunks: 64x32 each
      int l = t + 256 * i;
      int kk = l >> 5, c = l & 31;
      wsz[kk][c] = Wz[(k0 + kk) * 32 + c];
      wsr[kk][c] = Wr[(k0 + kk) * 32 + c];
      wsh[kk][c] = Wh[(k0 + kk) * 32 + c];
    }
    __syncthreads();
#pragma unroll 4
    for (int kk = 0; kk < 64; kk++) {
      float wz = wsz[kk][cg], wr = wsr[kk][cg], wh = wsh[kk][cg];
#pragma unroll
      for (int r = 0; r < 4; r++) {
        float xv = xs[rg + r][kk];
        acc[r][0] = fmaf(xv, wz, acc[r][0]);
        acc[r][1] = fmaf(xv, wr, acc[r][1]);
        acc[r][2] = fmaf(xv, wh, acc[r][2]);
      }
    }
    __syncthreads();
  }
#pragma unroll
  for (int r = 0; r < 4; r++) {
    size_t base = (size_t)(row0 + rg + r) * 96 + cg;
    XW[base]      = acc[r][0];
    XW[base + 32] = acc[r][1];
    XW[base + 64] = acc[r][2];
  }
}

// ---------------------------------------------------------------------------
// deg[dst] += w  (weighted in-degree, self-loop +1 added in dis kernel)
// ---------------------------------------------------------------------------
__global__ void deg_kernel(const int* __restrict__ ei, const float* __restrict__ w,
                           float* __restrict__ deg, int E) {
  int stride = gridDim.x * blockDim.x;
  for (int e = blockIdx.x * blockDim.x + threadIdx.x; e < E; e += stride)
    atomicAdd(&deg[ei[E + e]], w[e]);
}

__global__ void dis_kernel(const float* __restrict__ deg, float* __restrict__ dis, int n) {
  int i = blockIdx.x * blockDim.x + threadIdx.x;
  if (i < n) dis[i] = rsqrtf(deg[i] + 1.0f);
}

// ---------------------------------------------------------------------------
// Edge scatter: agg[dst,:] += dis[src]*w*dis[dst] * XW[src,:]
// 32 lanes per edge, 3 features per lane.
// ---------------------------------------------------------------------------
__global__ __launch_bounds__(256) void scatter_kernel(
    const int* __restrict__ ei, const float* __restrict__ w,
    const float* __restrict__ dis, const float* __restrict__ XW,
    float* __restrict__ agg, int E) {
  const int lane = threadIdx.x & 31;
  const int group = (blockIdx.x * blockDim.x + threadIdx.x) >> 5;
  const int ngroups = (gridDim.x * blockDim.x) >> 5;
  for (int e = group; e < E; e += ngroups) {
    int src = ei[e], dst = ei[E + e];
    float nrm = dis[src] * w[e] * dis[dst];
    size_t bs = (size_t)src * 96, bd = (size_t)dst * 96;
#pragma unroll
    for (int jj = 0; jj < 3; jj++) {
      int c = lane + 32 * jj;
      atomicAdd(&agg[bd + c], nrm * XW[bs + c]);
    }
  }
}

// ---------------------------------------------------------------------------
// Fuse: per node, add self-loop + bias, GRU gates, head.
// 256 threads = 8 groups of 32 lanes; group g owns node oct*8+g, lane j owns
// output feature j. Node vectors staged in LDS (broadcast reads), weights in LDS.
// ---------------------------------------------------------------------------
__global__ __launch_bounds__(256) void fuse_kernel(
    const float* __restrict__ agg, const float* __restrict__ XW,
    const float* __restrict__ dis, const float* __restrict__ Hp,
    const float* __restrict__ bz, const float* __restrict__ br, const float* __restrict__ bh,
    const float* __restrict__ LzW, const float* __restrict__ Lzb,
    const float* __restrict__ LrW, const float* __restrict__ Lrb,
    const float* __restrict__ LhW, const float* __restrict__ Lhb,
    const float* __restrict__ hW, const float* __restrict__ hb,
    float* __restrict__ outY, float* __restrict__ outH, int nOct) {
  __shared__ float sLz[2048], sLr[2048], sLh[2048];   // 24 KB
  __shared__ float sbz[32], sbr[32], sbh[32], sLzb[32], sLrb[32], sLhb[32], shW[32];
  __shared__ float sgz[8][33], sgr[8][33], sgh[8][33], shp[8][33], shr[8][33];
  __shared__ float shb;
  const int t = threadIdx.x;
  for (int i = t; i < 2048; i += 256) { sLz[i] = LzW[i]; sLr[i] = LrW[i]; sLh[i] = LhW[i]; }
  if (t < 32) {
    sbz[t] = bz[t]; sbr[t] = br[t]; sbh[t] = bh[t];
    sLzb[t] = Lzb[t]; sLrb[t] = Lrb[t]; sLhb[t] = Lhb[t]; shW[t] = hW[t];
  }
  if (t == 0) shb = hb[0];
  const int g = t >> 5;
  const int j = t & 31;
  for (int oct = blockIdx.x; oct < nOct; oct += gridDim.x) {
    const int n = oct * 8 + g;              // 12500 octets * 8 = 100000 exactly
    __syncthreads();                        // weights ready / sg* reuse safe
    {
      size_t b96 = (size_t)n * 96;
      float d = dis[n], d2 = d * d;
      sgz[g][j] = agg[b96 + j]      + d2 * XW[b96 + j]      + sbz[j];
      sgr[g][j] = agg[b96 + 32 + j] + d2 * XW[b96 + 32 + j] + sbr[j];
      sgh[g][j] = agg[b96 + 64 + j] + d2 * XW[b96 + 64 + j] + sbh[j];
      shp[g][j] = Hp[(size_t)n * 32 + j];
    }
    __syncthreads();
    float z = sLzb[j], r = sLrb[j];
#pragma unroll
    for (int k = 0; k < 32; k++) {
      z = fmaf(sgz[g][k], sLz[k * 32 + j], z);
      z = fmaf(shp[g][k], sLz[(k + 32) * 32 + j], z);
      r = fmaf(sgr[g][k], sLr[k * 32 + j], r);
      r = fmaf(shp[g][k], sLr[(k + 32) * 32 + j], r);
    }
    float Zg = 1.f / (1.f + expf(-z));
    float Rg = 1.f / (1.f + expf(-r));
    shr[g][j] = shp[g][j] * Rg;
    __syncthreads();
    float s = sLhb[j];
#pragma unroll
    for (int k = 0; k < 32; k++) {
      s = fmaf(sgh[g][k], sLh[k * 32 + j], s);
      s = fmaf(shr[g][k], sLh[(k + 32) * 32 + j], s);
    }
    float ht = tanhf(s);
    float h = Zg * shp[g][j] + (1.f - Zg) * ht;
    outH[(size_t)n * 32 + j] = h;
    float c = fmaxf(h, 0.f) * shW[j];
#pragma unroll
    for (int off = 16; off > 0; off >>= 1) c += __shfl_xor(c, off, 32);
    if (j == 0) outY[n] = c;
  }
}

// ---------------------------------------------------------------------------
extern "C" void kernel_launch(void* const* d_in, const int* in_sizes, int n_in,
                              void* d_out, int out_size, void* d_ws, size_t ws_size,
                              hipStream_t stream) {
  const float* x    = (const float*)d_in[0];
  const int*   ei   = (const int*)d_in[1];
  const float* w    = (const float*)d_in[2];
  const float* Hp   = (const float*)d_in[3];
  const float* Wz   = (const float*)d_in[4];
  const float* bz   = (const float*)d_in[5];
  const float* Wr   = (const float*)d_in[6];
  const float* br   = (const float*)d_in[7];
  const float* Wh   = (const float*)d_in[8];
  const float* bh   = (const float*)d_in[9];
  const float* LzW  = (const float*)d_in[10];
  const float* Lzb  = (const float*)d_in[11];
  const float* LrW  = (const float*)d_in[12];
  const float* Lrb  = (const float*)d_in[13];
  const float* LhW  = (const float*)d_in[14];
  const float* Lhb  = (const float*)d_in[15];
  const float* hW   = (const float*)d_in[16];
  const float* hb   = (const float*)d_in[17];

  const int N = N_NODES;
  const int E = in_sizes[2];

  float* ws  = (float*)d_ws;
  float* XW  = ws;                       // N*96
  float* agg = ws + (size_t)N * 96;      // N*96
  float* deg = agg + (size_t)N * 96;     // N
  float* dis = deg + N;                  // N

  float* outY = (float*)d_out;           // N
  float* outH = outY + N;                // N*32

  hipMemsetAsync(agg, 0, (size_t)N * 96 * sizeof(float), stream);
  hipMemsetAsync(deg, 0, (size_t)N * sizeof(float), stream);

  deg_kernel<<<2048, 256, 0, stream>>>(ei, w, deg, E);
  dis_kernel<<<(N + 255) / 256, 256, 0, stream>>>(deg, dis, N);
  gemm_xw<<<N / 32, 256, 0, stream>>>(x, Wz, Wr, Wh, XW);
  scatter_kernel<<<8192, 256, 0, stream>>>(ei, w, dis, XW, agg, E);
  fuse_kernel<<<1024, 256, 0, stream>>>(agg, XW, dis, Hp,
                                        bz, br, bh,
                                        LzW, Lzb, LrW, Lrb, LhW, Lhb,
                                        hW, hb, outY, outH, N / 8);
}

// Round 2
// 828.702 us; speedup vs baseline: 1.6122x; 1.6122x over previous
//
#include <hip/hip_runtime.h>
#include <math.h>

#define N_NODES 100000
#define F_INDIM 256
#define HDIM 32

// ---------------------------------------------------------------------------
// GEMM: XW[N,96] = x[N,256] @ [Wz | Wr | Wh]   (cols 0-31 = z, 32-63 = r, 64-95 = h)
// ---------------------------------------------------------------------------
__global__ __launch_bounds__(256) void gemm_xw(
    const float* __restrict__ x,
    const float* __restrict__ Wz, const float* __restrict__ Wr, const float* __restrict__ Wh,
    float* __restrict__ XW) {
  __shared__ float xs[32][64];
  __shared__ float wsz[64][32];
  __shared__ float wsr[64][32];
  __shared__ float wsh[64][32];
  const int t = threadIdx.x;
  const int row0 = blockIdx.x * 32;
  const int cg = t & 31;
  const int rg = (t >> 5) * 4;
  float acc[4][3] = {};
  for (int k0 = 0; k0 < 256; k0 += 64) {
#pragma unroll
    for (int i = 0; i < 8; i++) {
      int l = t + 256 * i;
      int r = l >> 6, kk = l & 63;
      xs[r][kk] = x[(size_t)(row0 + r) * F_INDIM + k0 + kk];
    }
#pragma unroll
    for (int i = 0; i < 8; i++) {
      int l = t + 256 * i;
      int kk = l >> 5, c = l & 31;
      wsz[kk][c] = Wz[(k0 + kk) * 32 + c];
      wsr[kk][c] = Wr[(k0 + kk) * 32 + c];
      wsh[kk][c] = Wh[(k0 + kk) * 32 + c];
    }
    __syncthreads();
#pragma unroll 4
    for (int kk = 0; kk < 64; kk++) {
      float wz = wsz[kk][cg], wr = wsr[kk][cg], wh = wsh[kk][cg];
#pragma unroll
      for (int r = 0; r < 4; r++) {
        float xv = xs[rg + r][kk];
        acc[r][0] = fmaf(xv, wz, acc[r][0]);
        acc[r][1] = fmaf(xv, wr, acc[r][1]);
        acc[r][2] = fmaf(xv, wh, acc[r][2]);
      }
    }
    __syncthreads();
  }
#pragma unroll
  for (int r = 0; r < 4; r++) {
    size_t base = (size_t)(row0 + rg + r) * 96 + cg;
    XW[base]      = acc[r][0];
    XW[base + 32] = acc[r][1];
    XW[base + 64] = acc[r][2];
  }
}

// ---------------------------------------------------------------------------
// Histogram: cnt[dst]++ and deg[dst] += w (atomics into 800 KB, L2-resident)
// ---------------------------------------------------------------------------
__global__ void histo_kernel(const int* __restrict__ ei, const float* __restrict__ w,
                             int* __restrict__ cnt, float* __restrict__ deg, int E) {
  int stride = gridDim.x * blockDim.x;
  for (int e = blockIdx.x * blockDim.x + threadIdx.x; e < E; e += stride) {
    int dst = ei[E + e];
    atomicAdd(&cnt[dst], 1);
    atomicAdd(&deg[dst], w[e]);
  }
}

__global__ void dis_kernel(const float* __restrict__ deg, float* __restrict__ dis, int n) {
  int i = blockIdx.x * blockDim.x + threadIdx.x;
  if (i < n) dis[i] = rsqrtf(deg[i] + 1.0f);
}

// ---------------------------------------------------------------------------
// Exclusive scan of cnt -> rowstart (3 kernels)
// ---------------------------------------------------------------------------
__global__ __launch_bounds__(512) void scan_block(const int* __restrict__ cnt,
                                                  int* __restrict__ rowstart,
                                                  int* __restrict__ partials, int n) {
  __shared__ int s[512];
  int t = threadIdx.x, i = blockIdx.x * 512 + t;
  int v = (i < n) ? cnt[i] : 0;
  s[t] = v;
  __syncthreads();
  for (int off = 1; off < 512; off <<= 1) {
    int x = (t >= off) ? s[t - off] : 0;
    __syncthreads();
    s[t] += x;
    __syncthreads();
  }
  if (i < n) rowstart[i] = s[t] - v;   // exclusive, block-local
  if (t == 511) partials[blockIdx.x] = s[511];
}

__global__ __launch_bounds__(256) void scan_partials(const int* __restrict__ partials,
                                                     int* __restrict__ pOff, int np) {
  __shared__ int s[256];
  int t = threadIdx.x;
  int v = (t < np) ? partials[t] : 0;
  s[t] = v;
  __syncthreads();
  for (int off = 1; off < 256; off <<= 1) {
    int x = (t >= off) ? s[t - off] : 0;
    __syncthreads();
    s[t] += x;
    __syncthreads();
  }
  if (t < np) pOff[t] = s[t] - v;      // exclusive
}

__global__ void add_offsets(int* __restrict__ rowstart, const int* __restrict__ pOff,
                            int* __restrict__ cursor, int n) {
  int i = blockIdx.x * blockDim.x + threadIdx.x;
  if (i < n) {
    int r = rowstart[i] + pOff[i >> 9];
    rowstart[i] = r;
    cursor[i] = r;
  }
}

// ---------------------------------------------------------------------------
// Scatter edges into CSR buckets: e2[pos] = (src, norm) packed 8B
// ---------------------------------------------------------------------------
__global__ void edge_scatter(const int* __restrict__ ei, const float* __restrict__ w,
                             const float* __restrict__ dis, int* __restrict__ cursor,
                             uint2* __restrict__ e2, int E) {
  int stride = gridDim.x * blockDim.x;
  for (int e = blockIdx.x * blockDim.x + threadIdx.x; e < E; e += stride) {
    int src = ei[e], dst = ei[E + e];
    float nrm = dis[src] * w[e] * dis[dst];
    int pos = atomicAdd(&cursor[dst], 1);
    e2[pos] = make_uint2((unsigned)src, __float_as_uint(nrm));
  }
}

// ---------------------------------------------------------------------------
// Fused gather + GRU + head. 256 threads = 8 groups of 32 lanes; group g owns
// node oct*8+g, lane j owns feature j. Gather accumulates 3 regs/lane over the
// node's CSR bucket (coalesced 128B row segments of XW, L3-resident).
// ---------------------------------------------------------------------------
__global__ __launch_bounds__(256) void gru_gather(
    const uint2* __restrict__ e2, const int* __restrict__ rowstart,
    const int* __restrict__ cnt,
    const float* __restrict__ XW, const float* __restrict__ dis,
    const float* __restrict__ Hp,
    const float* __restrict__ bz, const float* __restrict__ br, const float* __restrict__ bh,
    const float* __restrict__ LzW, const float* __restrict__ Lzb,
    const float* __restrict__ LrW, const float* __restrict__ Lrb,
    const float* __restrict__ LhW, const float* __restrict__ Lhb,
    const float* __restrict__ hW, const float* __restrict__ hb,
    float* __restrict__ outY, float* __restrict__ outH, int nOct) {
  __shared__ float sLz[2048], sLr[2048], sLh[2048];
  __shared__ float sbz[32], sbr[32], sbh[32], sLzb[32], sLrb[32], sLhb[32], shW[32];
  __shared__ float sgz[8][33], sgr[8][33], sgh[8][33], shp[8][33], shr[8][33];
  __shared__ float shb;
  const int t = threadIdx.x;
  for (int i = t; i < 2048; i += 256) { sLz[i] = LzW[i]; sLr[i] = LrW[i]; sLh[i] = LhW[i]; }
  if (t < 32) {
    sbz[t] = bz[t]; sbr[t] = br[t]; sbh[t] = bh[t];
    sLzb[t] = Lzb[t]; sLrb[t] = Lrb[t]; sLhb[t] = Lhb[t]; shW[t] = hW[t];
  }
  if (t == 0) shb = hb[0];
  const int g = t >> 5;
  const int j = t & 31;
  for (int oct = blockIdx.x; oct < nOct; oct += gridDim.x) {
    const int n = oct * 8 + g;
    // --- gather this node's in-edges (register-only, no LDS, no sync) ---
    const int start = rowstart[n];
    const int c = cnt[n];
    float a0 = 0.f, a1 = 0.f, a2 = 0.f;
    for (int e0 = 0; e0 < c; e0 += 32) {
      uint2 ed = make_uint2(0u, 0u);
      if (e0 + j < c) ed = e2[start + e0 + j];
      int m = (c - e0 < 32) ? (c - e0) : 32;
      for (int k = 0; k < m; k++) {
        int src = (int)__shfl(ed.x, k, 32);
        float nrm = __shfl(__uint_as_float(ed.y), k, 32);
        size_t bs = (size_t)src * 96;
        a0 = fmaf(nrm, XW[bs + j], a0);
        a1 = fmaf(nrm, XW[bs + 32 + j], a1);
        a2 = fmaf(nrm, XW[bs + 64 + j], a2);
      }
    }
    __syncthreads();   // weights ready (iter 0) / previous iter's LDS reads done
    {
      size_t b96 = (size_t)n * 96;
      float d = dis[n], d2 = d * d;
      sgz[g][j] = a0 + d2 * XW[b96 + j]      + sbz[j];
      sgr[g][j] = a1 + d2 * XW[b96 + 32 + j] + sbr[j];
      sgh[g][j] = a2 + d2 * XW[b96 + 64 + j] + sbh[j];
      shp[g][j] = Hp[(size_t)n * 32 + j];
    }
    __syncthreads();
    float z = sLzb[j], r = sLrb[j];
#pragma unroll
    for (int k = 0; k < 32; k++) {
      z = fmaf(sgz[g][k], sLz[k * 32 + j], z);
      z = fmaf(shp[g][k], sLz[(k + 32) * 32 + j], z);
      r = fmaf(sgr[g][k], sLr[k * 32 + j], r);
      r = fmaf(shp[g][k], sLr[(k + 32) * 32 + j], r);
    }
    float Zg = 1.f / (1.f + expf(-z));
    float Rg = 1.f / (1.f + expf(-r));
    shr[g][j] = shp[g][j] * Rg;
    __syncthreads();
    float s = sLhb[j];
#pragma unroll
    for (int k = 0; k < 32; k++) {
      s = fmaf(sgh[g][k], sLh[k * 32 + j], s);
      s = fmaf(shr[g][k], sLh[(k + 32) * 32 + j], s);
    }
    float ht = tanhf(s);
    float h = Zg * shp[g][j] + (1.f - Zg) * ht;
    outH[(size_t)n * 32 + j] = h;
    float cacc = fmaxf(h, 0.f) * shW[j];
#pragma unroll
    for (int off = 16; off > 0; off >>= 1) cacc += __shfl_xor(cacc, off, 32);
    if (j == 0) outY[n] = cacc + shb;
  }
}

// ---------------------------------------------------------------------------
extern "C" void kernel_launch(void* const* d_in, const int* in_sizes, int n_in,
                              void* d_out, int out_size, void* d_ws, size_t ws_size,
                              hipStream_t stream) {
  const float* x    = (const float*)d_in[0];
  const int*   ei   = (const int*)d_in[1];
  const float* w    = (const float*)d_in[2];
  const float* Hp   = (const float*)d_in[3];
  const float* Wz   = (const float*)d_in[4];
  const float* bz   = (const float*)d_in[5];
  const float* Wr   = (const float*)d_in[6];
  const float* br   = (const float*)d_in[7];
  const float* Wh   = (const float*)d_in[8];
  const float* bh   = (const float*)d_in[9];
  const float* LzW  = (const float*)d_in[10];
  const float* Lzb  = (const float*)d_in[11];
  const float* LrW  = (const float*)d_in[12];
  const float* Lrb  = (const float*)d_in[13];
  const float* LhW  = (const float*)d_in[14];
  const float* Lhb  = (const float*)d_in[15];
  const float* hW   = (const float*)d_in[16];
  const float* hb   = (const float*)d_in[17];

  const int N = N_NODES;
  const int E = in_sizes[2];

  char* wsb = (char*)d_ws;
  float* XW      = (float*)wsb;                          // N*96 f32   (38.4 MB)
  uint2* e2      = (uint2*)(wsb + (size_t)N * 96 * 4);   // E uint2    (25.6 MB)
  char*  p       = wsb + (size_t)N * 96 * 4 + (size_t)E * 8;
  int*   cnt     = (int*)p;            p += (size_t)N * 4;
  int*   rowstart= (int*)p;            p += (size_t)N * 4;
  int*   cursor  = (int*)p;            p += (size_t)N * 4;
  float* deg     = (float*)p;          p += (size_t)N * 4;
  float* dis     = (float*)p;          p += (size_t)N * 4;
  int*   partials= (int*)p;            p += 256 * 4;
  int*   pOff    = (int*)p;

  float* outY = (float*)d_out;           // N
  float* outH = outY + N;                // N*32

  hipMemsetAsync(cnt, 0, (size_t)N * sizeof(int), stream);
  hipMemsetAsync(deg, 0, (size_t)N * sizeof(float), stream);

  const int nScanBlocks = (N + 511) / 512;   // 196

  histo_kernel<<<2048, 256, 0, stream>>>(ei, w, cnt, deg, E);
  dis_kernel<<<(N + 255) / 256, 256, 0, stream>>>(deg, dis, N);
  scan_block<<<nScanBlocks, 512, 0, stream>>>(cnt, rowstart, partials, N);
  scan_partials<<<1, 256, 0, stream>>>(partials, pOff, nScanBlocks);
  add_offsets<<<(N + 255) / 256, 256, 0, stream>>>(rowstart, pOff, cursor, N);
  edge_scatter<<<2048, 256, 0, stream>>>(ei, w, dis, cursor, e2, E);
  gemm_xw<<<N / 32, 256, 0, stream>>>(x, Wz, Wr, Wh, XW);
  gru_gather<<<2048, 256, 0, stream>>>(e2, rowstart, cnt, XW, dis, Hp,
                                       bz, br, bh,
                                       LzW, Lzb, LrW, Lrb, LhW, Lhb,
                                       hW, hb, outY, outH, N / 8);
}

// Round 3
// 641.264 us; speedup vs baseline: 2.0835x; 1.2923x over previous
//
#include <hip/hip_runtime.h>
#include <math.h>

#define N_NODES 100000
#define F_INDIM 256
#define GEMM_BLOCKS (N_NODES / 32)   // 3125
#define HISTO_BLOCKS 2048

// pack two f32 into bf16 pair (RNE), lo = a, hi = b
__device__ __forceinline__ unsigned bf16pack(float a, float b) {
  unsigned ua = __float_as_uint(a);
  ua += 0x7FFFu + ((ua >> 16) & 1u);
  unsigned ub = __float_as_uint(b);
  ub += 0x7FFFu + ((ub >> 16) & 1u);
  return (ub & 0xFFFF0000u) | (ua >> 16);
}

// ---------------------------------------------------------------------------
// Heterogeneous kernel: blocks [0,GEMM_BLOCKS) compute XWb = x @ [Wz|Wr|Wh]
// (bf16-pair packed, row = 48 uints: pairs [z0..z15 | r0..r15 | h0..h15]);
// blocks [GEMM_BLOCKS, +HISTO_BLOCKS) histogram dst and record each edge's
// rank: drank[e] = (rank<<17)|dst  (one returning atomic per edge).
// ---------------------------------------------------------------------------
__global__ __launch_bounds__(256) void gemm_histo(
    const float* __restrict__ x,
    const float* __restrict__ Wz, const float* __restrict__ Wr, const float* __restrict__ Wh,
    unsigned* __restrict__ XWb,
    const int* __restrict__ ei, unsigned* __restrict__ cnt, unsigned* __restrict__ drank,
    int E) {
  __shared__ float xs[32][64];
  __shared__ float wsz[64][32];
  __shared__ float wsr[64][32];
  __shared__ float wsh[64][32];
  const int t = threadIdx.x;
  if (blockIdx.x >= GEMM_BLOCKS) {
    int e0 = (blockIdx.x - GEMM_BLOCKS) * 256 + t;
    int stride = HISTO_BLOCKS * 256;
    for (int e = e0; e < E; e += stride) {
      int dst = ei[E + e];
      unsigned r = atomicAdd(&cnt[dst], 1u);
      drank[e] = (r << 17) | (unsigned)dst;
    }
    return;
  }
  const int row0 = blockIdx.x * 32;
  const int cg = t & 31;
  const int rg = (t >> 5) * 4;
  float acc[4][3] = {};
  for (int k0 = 0; k0 < 256; k0 += 64) {
#pragma unroll
    for (int i = 0; i < 8; i++) {
      int l = t + 256 * i;
      int r = l >> 6, kk = l & 63;
      xs[r][kk] = x[(size_t)(row0 + r) * F_INDIM + k0 + kk];
    }
#pragma unroll
    for (int i = 0; i < 8; i++) {
      int l = t + 256 * i;
      int kk = l >> 5, c = l & 31;
      wsz[kk][c] = Wz[(k0 + kk) * 32 + c];
      wsr[kk][c] = Wr[(k0 + kk) * 32 + c];
      wsh[kk][c] = Wh[(k0 + kk) * 32 + c];
    }
    __syncthreads();
#pragma unroll 4
    for (int kk = 0; kk < 64; kk++) {
      float wz = wsz[kk][cg], wr = wsr[kk][cg], wh = wsh[kk][cg];
#pragma unroll
      for (int r = 0; r < 4; r++) {
        float xv = xs[rg + r][kk];
        acc[r][0] = fmaf(xv, wz, acc[r][0]);
        acc[r][1] = fmaf(xv, wr, acc[r][1]);
        acc[r][2] = fmaf(xv, wh, acc[r][2]);
      }
    }
    __syncthreads();
  }
#pragma unroll
  for (int r = 0; r < 4; r++) {
    int row = row0 + rg + r;
#pragma unroll
    for (int g2 = 0; g2 < 3; g2++) {
      float other = __shfl_xor(acc[r][g2], 1);
      if ((cg & 1) == 0)
        XWb[(size_t)row * 48 + g2 * 16 + (cg >> 1)] = bf16pack(acc[r][g2], other);
    }
  }
}

// ---------------------------------------------------------------------------
// Exclusive scan of cnt -> rowstart
// ---------------------------------------------------------------------------
__global__ __launch_bounds__(512) void scan_block(const unsigned* __restrict__ cnt,
                                                  int* __restrict__ rowstart,
                                                  int* __restrict__ partials, int n) {
  __shared__ int s[512];
  int t = threadIdx.x, i = blockIdx.x * 512 + t;
  int v = (i < n) ? (int)cnt[i] : 0;
  s[t] = v;
  __syncthreads();
  for (int off = 1; off < 512; off <<= 1) {
    int xv = (t >= off) ? s[t - off] : 0;
    __syncthreads();
    s[t] += xv;
    __syncthreads();
  }
  if (i < n) rowstart[i] = s[t] - v;
  if (t == 511) partials[blockIdx.x] = s[511];
}

__global__ __launch_bounds__(256) void scan_partials(const int* __restrict__ partials,
                                                     int* __restrict__ pOff, int np) {
  __shared__ int s[256];
  int t = threadIdx.x;
  int v = (t < np) ? partials[t] : 0;
  s[t] = v;
  __syncthreads();
  for (int off = 1; off < 256; off <<= 1) {
    int xv = (t >= off) ? s[t - off] : 0;
    __syncthreads();
    s[t] += xv;
    __syncthreads();
  }
  if (t < np) pOff[t] = s[t] - v;
}

__global__ void add_offsets(int* __restrict__ rowstart, const int* __restrict__ pOff, int n) {
  int i = blockIdx.x * blockDim.x + threadIdx.x;
  if (i < n) rowstart[i] += pOff[i >> 9];
}

// ---------------------------------------------------------------------------
// Place edges into CSR buckets (no atomics): pos = rowstart[dst] + rank
// ---------------------------------------------------------------------------
__global__ void edge_place(const int* __restrict__ ei, const float* __restrict__ w,
                           const unsigned* __restrict__ drank, const int* __restrict__ rowstart,
                           uint2* __restrict__ e2, int E) {
  int stride = gridDim.x * blockDim.x;
  for (int e = blockIdx.x * blockDim.x + threadIdx.x; e < E; e += stride) {
    unsigned dr = drank[e];
    int dst = (int)(dr & 0x1FFFFu);
    int rank = (int)(dr >> 17);
    int pos = rowstart[dst] + rank;
    e2[pos] = make_uint2((unsigned)ei[e], __float_as_uint(w[e]));
  }
}

// ---------------------------------------------------------------------------
// deg/dis from CSR buckets: one wave per node, lanes stride the bucket.
// ---------------------------------------------------------------------------
__global__ __launch_bounds__(256) void deg_dis(const uint2* __restrict__ e2,
                                               const int* __restrict__ rowstart,
                                               const unsigned* __restrict__ cnt,
                                               float* __restrict__ dis, int N) {
  int wid = (blockIdx.x * blockDim.x + threadIdx.x) >> 6;
  int nw = (gridDim.x * blockDim.x) >> 6;
  int l = threadIdx.x & 63;
  for (int n = wid; n < N; n += nw) {
    int start = rowstart[n], c = (int)cnt[n];
    float s = 0.f;
    for (int i = l; i < c; i += 64) s += __uint_as_float(e2[start + i].y);
#pragma unroll
    for (int off = 32; off > 0; off >>= 1) s += __shfl_xor(s, off);
    if (l == 0) dis[n] = rsqrtf(s + 1.0f);
  }
}

// ---------------------------------------------------------------------------
// Fused gather + GRU + head. ONE WAVE64 PER NODE (no divergence between
// 32-lane halves, no __syncthreads in the loop — per-wave private LDS).
// Gather: lane l<48 owns bf16 feature pair (2l, 2l+1) of the 96 gate features.
// GRU: half 0 (lanes 0-31) computes z, half 1 computes r in parallel; the
// h-tilde dot product is split across halves and combined with shfl_xor(32).
// ---------------------------------------------------------------------------
__global__ __launch_bounds__(256) void gru_gather(
    const uint2* __restrict__ e2, const int* __restrict__ rowstart,
    const unsigned* __restrict__ cnt, const unsigned* __restrict__ XWb,
    const float* __restrict__ dis, const float* __restrict__ Hp,
    const float* __restrict__ bz, const float* __restrict__ br, const float* __restrict__ bh,
    const float* __restrict__ LzW, const float* __restrict__ Lzb,
    const float* __restrict__ LrW, const float* __restrict__ Lrb,
    const float* __restrict__ LhW, const float* __restrict__ Lhb,
    const float* __restrict__ hW, const float* __restrict__ hb,
    float* __restrict__ outY, float* __restrict__ outH, int N) {
  __shared__ float sLz[2048], sLr[2048], sLh[2048];   // 24 KB
  __shared__ float sb96[96];
  __shared__ float sLzb[32], sLrb[32], sLhb[32], shW[32];
  __shared__ float2 sg2[4][48];                       // per-wave gather result (96 feats)
  __shared__ float shp[4][32], shr[4][32];
  __shared__ float shb;
  const int t = threadIdx.x;
  for (int i = t; i < 2048; i += 256) { sLz[i] = LzW[i]; sLr[i] = LrW[i]; sLh[i] = LhW[i]; }
  if (t < 32) {
    sb96[t] = bz[t]; sb96[32 + t] = br[t]; sb96[64 + t] = bh[t];
    sLzb[t] = Lzb[t]; sLrb[t] = Lrb[t]; sLhb[t] = Lhb[t]; shW[t] = hW[t];
  }
  if (t == 0) shb = hb[0];
  __syncthreads();
  const int ws = t >> 6;          // wave slot in block
  const int l = t & 63;
  const int lp = (l < 48) ? l : 47;
  const int j = l & 31;
  const int half = l >> 5;
  const float* sgf = (const float*)&sg2[ws][0];
  int wid = blockIdx.x * 4 + ws;
  int nw = gridDim.x * 4;
  for (int n = wid; n < N; n += nw) {
    const int start = rowstart[n];
    const int c = (int)cnt[n];
    const float d = dis[n];
    float a0 = 0.f, a1 = 0.f;
    for (int e0 = 0; e0 < c; e0 += 64) {
      uint2 ed = make_uint2(0u, 0u);
      float pw = 0.f;
      if (e0 + l < c) {
        ed = e2[start + e0 + l];
        pw = __uint_as_float(ed.y) * dis[ed.x];      // w * dis[src]
      }
      int m = c - e0; if (m > 64) m = 64;
      for (int k = 0; k < m; k++) {
        int srck = __shfl((int)ed.x, k);
        float nrm = __shfl(pw, k) * d;               // * dis[dst]
        unsigned v = XWb[(size_t)srck * 48 + lp];
        a0 = fmaf(nrm, __uint_as_float(v << 16), a0);
        a1 = fmaf(nrm, __uint_as_float(v & 0xFFFF0000u), a1);
      }
    }
    {   // self-loop + bias
      unsigned v = XWb[(size_t)n * 48 + lp];
      float d2 = d * d;
      a0 = fmaf(d2, __uint_as_float(v << 16), a0) + sb96[2 * lp];
      a1 = fmaf(d2, __uint_as_float(v & 0xFFFF0000u), a1) + sb96[2 * lp + 1];
    }
    if (l < 48) sg2[ws][l] = make_float2(a0, a1);
    float hpj = 0.f;
    if (l < 32) { hpj = Hp[(size_t)n * 32 + l]; shp[ws][l] = hpj; }
    // z (half 0) and r (half 1) gates in parallel
    const float* Wm = half ? sLr : sLz;
    const float* gsel = half ? (sgf + 32) : sgf;
    float val = half ? sLrb[j] : sLzb[j];
#pragma unroll
    for (int k = 0; k < 32; k++) {
      val = fmaf(gsel[k], Wm[k * 32 + j], val);
      val = fmaf(shp[ws][k], Wm[(k + 32) * 32 + j], val);
    }
    float gate = 1.f / (1.f + __expf(-val));         // Z (half0) / R (half1)
    if (half) shr[ws][j] = shp[ws][j] * gate;
    // h-tilde pre-activation, split across halves
    float s = half ? 0.f : sLhb[j];
#pragma unroll
    for (int k = 0; k < 32; k++) {
      float a = half ? shr[ws][k] : sgf[64 + k];
      s = fmaf(a, sLh[(half ? (k + 32) : k) * 32 + j], s);
    }
    s += __shfl_xor(s, 32);
    if (!half) {
      float ht = tanhf(s);
      float h = gate * hpj + (1.f - gate) * ht;
      outH[(size_t)n * 32 + j] = h;
      float cacc = fmaxf(h, 0.f) * shW[j];
#pragma unroll
      for (int off = 16; off > 0; off >>= 1) cacc += __shfl_xor(cacc, off, 32);
      if (j == 0) outY[n] = cacc + shb;
    }
  }
}

// ---------------------------------------------------------------------------
extern "C" void kernel_launch(void* const* d_in, const int* in_sizes, int n_in,
                              void* d_out, int out_size, void* d_ws, size_t ws_size,
                              hipStream_t stream) {
  const float* x    = (const float*)d_in[0];
  const int*   ei   = (const int*)d_in[1];
  const float* w    = (const float*)d_in[2];
  const float* Hp   = (const float*)d_in[3];
  const float* Wz   = (const float*)d_in[4];
  const float* bz   = (const float*)d_in[5];
  const float* Wr   = (const float*)d_in[6];
  const float* br   = (const float*)d_in[7];
  const float* Wh   = (const float*)d_in[8];
  const float* bh   = (const float*)d_in[9];
  const float* LzW  = (const float*)d_in[10];
  const float* Lzb  = (const float*)d_in[11];
  const float* LrW  = (const float*)d_in[12];
  const float* Lrb  = (const float*)d_in[13];
  const float* LhW  = (const float*)d_in[14];
  const float* Lhb  = (const float*)d_in[15];
  const float* hW   = (const float*)d_in[16];
  const float* hb   = (const float*)d_in[17];

  const int N = N_NODES;
  const int E = in_sizes[2];

  char* p = (char*)d_ws;
  unsigned* XWb   = (unsigned*)p;  p += (size_t)N * 48 * 4;   // 19.2 MB
  uint2*    e2    = (uint2*)p;     p += (size_t)E * 8;        // 25.6 MB
  unsigned* drank = (unsigned*)p;  p += (size_t)E * 4;        // 12.8 MB
  unsigned* cnt   = (unsigned*)p;  p += (size_t)N * 4;
  int* rowstart   = (int*)p;       p += (size_t)N * 4;
  float* dis      = (float*)p;     p += (size_t)N * 4;
  int* partials   = (int*)p;       p += 256 * 4;
  int* pOff       = (int*)p;

  float* outY = (float*)d_out;           // N
  float* outH = outY + N;                // N*32

  hipMemsetAsync(cnt, 0, (size_t)N * sizeof(unsigned), stream);

  const int nScanBlocks = (N + 511) / 512;   // 196

  gemm_histo<<<GEMM_BLOCKS + HISTO_BLOCKS, 256, 0, stream>>>(
      x, Wz, Wr, Wh, XWb, ei, cnt, drank, E);
  scan_block<<<nScanBlocks, 512, 0, stream>>>(cnt, rowstart, partials, N);
  scan_partials<<<1, 256, 0, stream>>>(partials, pOff, nScanBlocks);
  add_offsets<<<(N + 255) / 256, 256, 0, stream>>>(rowstart, pOff, N);
  edge_place<<<2048, 256, 0, stream>>>(ei, w, drank, rowstart, e2, E);
  deg_dis<<<2048, 256, 0, stream>>>(e2, rowstart, cnt, dis, N);
  gru_gather<<<2048, 256, 0, stream>>>(e2, rowstart, cnt, XWb, dis, Hp,
                                       bz, br, bh,
                                       LzW, Lzb, LrW, Lrb, LhW, Lhb,
                                       hW, hb, outY, outH, N);
}

// Round 4
// 454.177 us; speedup vs baseline: 2.9417x; 1.4119x over previous
//
#include <hip/hip_runtime.h>
#include <math.h>

#define N_NODES 100000
#define F_INDIM 256
#define GEMM_BLOCKS (N_NODES / 32)   // 3125
#define HISTO_BLOCKS 2048

// pack two f32 into bf16 pair (RNE), lo = a, hi = b
__device__ __forceinline__ unsigned bf16pack(float a, float b) {
  unsigned ua = __float_as_uint(a);
  ua += 0x7FFFu + ((ua >> 16) & 1u);
  unsigned ub = __float_as_uint(b);
  ub += 0x7FFFu + ((ub >> 16) & 1u);
  return (ub & 0xFFFF0000u) | (ua >> 16);
}
__device__ __forceinline__ float lo16(unsigned v) { return __uint_as_float(v << 16); }
__device__ __forceinline__ float hi16(unsigned v) { return __uint_as_float(v & 0xFFFF0000u); }

// ---------------------------------------------------------------------------
// Heterogeneous kernel: blocks [0,GEMM_BLOCKS) compute XWb = x @ [Wz|Wr|Wh]
// (bf16-pair packed, row = 48 uints); blocks [GEMM_BLOCKS,+HISTO_BLOCKS)
// histogram dst and record each edge's rank (one returning atomic per edge).
// ---------------------------------------------------------------------------
__global__ __launch_bounds__(256) void gemm_histo(
    const float* __restrict__ x,
    const float* __restrict__ Wz, const float* __restrict__ Wr, const float* __restrict__ Wh,
    unsigned* __restrict__ XWb,
    const int* __restrict__ ei, unsigned* __restrict__ cnt, unsigned* __restrict__ drank,
    int E) {
  __shared__ float xs[32][64];
  __shared__ float wsz[64][32];
  __shared__ float wsr[64][32];
  __shared__ float wsh[64][32];
  const int t = threadIdx.x;
  if (blockIdx.x >= GEMM_BLOCKS) {
    int e0 = (blockIdx.x - GEMM_BLOCKS) * 256 + t;
    int stride = HISTO_BLOCKS * 256;
    for (int e = e0; e < E; e += stride) {
      int dst = ei[E + e];
      unsigned r = atomicAdd(&cnt[dst], 1u);
      drank[e] = (r << 17) | (unsigned)dst;
    }
    return;
  }
  const int row0 = blockIdx.x * 32;
  const int cg = t & 31;
  const int rg = (t >> 5) * 4;
  float acc[4][3] = {};
  for (int k0 = 0; k0 < 256; k0 += 64) {
#pragma unroll
    for (int i = 0; i < 8; i++) {
      int l = t + 256 * i;
      int r = l >> 6, kk = l & 63;
      xs[r][kk] = x[(size_t)(row0 + r) * F_INDIM + k0 + kk];
    }
#pragma unroll
    for (int i = 0; i < 8; i++) {
      int l = t + 256 * i;
      int kk = l >> 5, c = l & 31;
      wsz[kk][c] = Wz[(k0 + kk) * 32 + c];
      wsr[kk][c] = Wr[(k0 + kk) * 32 + c];
      wsh[kk][c] = Wh[(k0 + kk) * 32 + c];
    }
    __syncthreads();
#pragma unroll 4
    for (int kk = 0; kk < 64; kk++) {
      float wz = wsz[kk][cg], wr = wsr[kk][cg], wh = wsh[kk][cg];
#pragma unroll
      for (int r = 0; r < 4; r++) {
        float xv = xs[rg + r][kk];
        acc[r][0] = fmaf(xv, wz, acc[r][0]);
        acc[r][1] = fmaf(xv, wr, acc[r][1]);
        acc[r][2] = fmaf(xv, wh, acc[r][2]);
      }
    }
    __syncthreads();
  }
#pragma unroll
  for (int r = 0; r < 4; r++) {
    int row = row0 + rg + r;
#pragma unroll
    for (int g2 = 0; g2 < 3; g2++) {
      float other = __shfl_xor(acc[r][g2], 1);
      if ((cg & 1) == 0)
        XWb[(size_t)row * 48 + g2 * 16 + (cg >> 1)] = bf16pack(acc[r][g2], other);
    }
  }
}

// ---------------------------------------------------------------------------
// Exclusive scan of cnt -> rowstart
// ---------------------------------------------------------------------------
__global__ __launch_bounds__(512) void scan_block(const unsigned* __restrict__ cnt,
                                                  int* __restrict__ rowstart,
                                                  int* __restrict__ partials, int n) {
  __shared__ int s[512];
  int t = threadIdx.x, i = blockIdx.x * 512 + t;
  int v = (i < n) ? (int)cnt[i] : 0;
  s[t] = v;
  __syncthreads();
  for (int off = 1; off < 512; off <<= 1) {
    int xv = (t >= off) ? s[t - off] : 0;
    __syncthreads();
    s[t] += xv;
    __syncthreads();
  }
  if (i < n) rowstart[i] = s[t] - v;
  if (t == 511) partials[blockIdx.x] = s[511];
}

__global__ __launch_bounds__(256) void scan_partials(const int* __restrict__ partials,
                                                     int* __restrict__ pOff, int np) {
  __shared__ int s[256];
  int t = threadIdx.x;
  int v = (t < np) ? partials[t] : 0;
  s[t] = v;
  __syncthreads();
  for (int off = 1; off < 256; off <<= 1) {
    int xv = (t >= off) ? s[t - off] : 0;
    __syncthreads();
    s[t] += xv;
    __syncthreads();
  }
  if (t < np) pOff[t] = s[t] - v;
}

__global__ void add_offsets(int* __restrict__ rowstart, const int* __restrict__ pOff, int n) {
  int i = blockIdx.x * blockDim.x + threadIdx.x;
  if (i < n) rowstart[i] += pOff[i >> 9];
}

// ---------------------------------------------------------------------------
// Place edges into CSR buckets (no atomics): pos = rowstart[dst] + rank
// ---------------------------------------------------------------------------
__global__ void edge_place(const int* __restrict__ ei, const float* __restrict__ w,
                           const unsigned* __restrict__ drank, const int* __restrict__ rowstart,
                           uint2* __restrict__ e2, int E) {
  int stride = gridDim.x * blockDim.x;
  for (int e = blockIdx.x * blockDim.x + threadIdx.x; e < E; e += stride) {
    unsigned dr = drank[e];
    int dst = (int)(dr & 0x1FFFFu);
    int rank = (int)(dr >> 17);
    int pos = rowstart[dst] + rank;
    e2[pos] = make_uint2((unsigned)ei[e], __float_as_uint(w[e]));
  }
}

// ---------------------------------------------------------------------------
// deg/dis from CSR buckets: one wave per node, lanes stride the bucket.
// ---------------------------------------------------------------------------
__global__ __launch_bounds__(256) void deg_dis(const uint2* __restrict__ e2,
                                               const int* __restrict__ rowstart,
                                               const unsigned* __restrict__ cnt,
                                               float* __restrict__ dis, int N) {
  int wid = (blockIdx.x * blockDim.x + threadIdx.x) >> 6;
  int nw = (gridDim.x * blockDim.x) >> 6;
  int l = threadIdx.x & 63;
  for (int n = wid; n < N; n += nw) {
    int start = rowstart[n], c = (int)cnt[n];
    float s = 0.f;
    for (int i = l; i < c; i += 64) s += __uint_as_float(e2[start + i].y);
#pragma unroll
    for (int off = 32; off > 0; off >>= 1) s += __shfl_xor(s, off);
    if (l == 0) dis[n] = rsqrtf(s + 1.0f);
  }
}

// ---------------------------------------------------------------------------
// Fused gather + GRU + head. One wave64 per node. Gather inner loop unrolled
// 8-wide (8 independent XWb row loads in flight). GRU weights bf16-packed in
// LDS (12 KB) -> ~16 KB LDS total, launch_bounds(256,6) for 24 waves/CU.
// ---------------------------------------------------------------------------
__global__ __launch_bounds__(256, 6) void gru_gather(
    const uint2* __restrict__ e2, const int* __restrict__ rowstart,
    const unsigned* __restrict__ cnt, const unsigned* __restrict__ XWb,
    const float* __restrict__ dis, const float* __restrict__ Hp,
    const float* __restrict__ bz, const float* __restrict__ br, const float* __restrict__ bh,
    const float* __restrict__ LzW, const float* __restrict__ Lzb,
    const float* __restrict__ LrW, const float* __restrict__ Lrb,
    const float* __restrict__ LhW, const float* __restrict__ Lhb,
    const float* __restrict__ hW, const float* __restrict__ hb,
    float* __restrict__ outY, float* __restrict__ outH, int N) {
  __shared__ unsigned sLz[1024], sLr[1024], sLh[1024];   // bf16-pair packed, 12 KB
  __shared__ float sb96[96];
  __shared__ float sLzb[32], sLrb[32], sLhb[32], shW[32];
  __shared__ float2 sg2[4][48];                          // per-wave gather (96 feats)
  __shared__ float shp[4][32], shr[4][32];
  __shared__ float shb;
  const int t = threadIdx.x;
  for (int i = t; i < 1024; i += 256) {
    int jj = i & 31, k2 = i >> 5;
    sLz[i] = bf16pack(LzW[(2 * k2) * 32 + jj], LzW[(2 * k2 + 1) * 32 + jj]);
    sLr[i] = bf16pack(LrW[(2 * k2) * 32 + jj], LrW[(2 * k2 + 1) * 32 + jj]);
    sLh[i] = bf16pack(LhW[(2 * k2) * 32 + jj], LhW[(2 * k2 + 1) * 32 + jj]);
  }
  if (t < 32) {
    sb96[t] = bz[t]; sb96[32 + t] = br[t]; sb96[64 + t] = bh[t];
    sLzb[t] = Lzb[t]; sLrb[t] = Lrb[t]; sLhb[t] = Lhb[t]; shW[t] = hW[t];
  }
  if (t == 0) shb = hb[0];
  __syncthreads();
  const int ws = t >> 6;
  const int l = t & 63;
  const int lp = (l < 48) ? l : 47;
  const int j = l & 31;
  const int half = l >> 5;
  const float* sgf = (const float*)&sg2[ws][0];
  int wid = blockIdx.x * 4 + ws;
  int nw = gridDim.x * 4;
  for (int n = wid; n < N; n += nw) {
    const int start = rowstart[n];
    const int c = (int)cnt[n];
    const float d = dis[n];
    float a0 = 0.f, a1 = 0.f;
    for (int e0 = 0; e0 < c; e0 += 64) {
      uint2 ed = make_uint2(0u, 0u);
      float pw = 0.f;
      if (e0 + l < c) {
        ed = e2[start + e0 + l];
        pw = __uint_as_float(ed.y) * dis[ed.x];      // w * dis[src]
      }
      int m = c - e0; if (m > 64) m = 64;
      int k = 0;
      for (; k + 8 <= m; k += 8) {                   // 8 loads in flight
        unsigned v0 = XWb[(size_t)__shfl((int)ed.x, k + 0) * 48 + lp];
        unsigned v1 = XWb[(size_t)__shfl((int)ed.x, k + 1) * 48 + lp];
        unsigned v2 = XWb[(size_t)__shfl((int)ed.x, k + 2) * 48 + lp];
        unsigned v3 = XWb[(size_t)__shfl((int)ed.x, k + 3) * 48 + lp];
        unsigned v4 = XWb[(size_t)__shfl((int)ed.x, k + 4) * 48 + lp];
        unsigned v5 = XWb[(size_t)__shfl((int)ed.x, k + 5) * 48 + lp];
        unsigned v6 = XWb[(size_t)__shfl((int)ed.x, k + 6) * 48 + lp];
        unsigned v7 = XWb[(size_t)__shfl((int)ed.x, k + 7) * 48 + lp];
        float n0 = __shfl(pw, k + 0), n1 = __shfl(pw, k + 1);
        float n2 = __shfl(pw, k + 2), n3 = __shfl(pw, k + 3);
        float n4 = __shfl(pw, k + 4), n5 = __shfl(pw, k + 5);
        float n6 = __shfl(pw, k + 6), n7 = __shfl(pw, k + 7);
        a0 = fmaf(n0, lo16(v0), a0); a1 = fmaf(n0, hi16(v0), a1);
        a0 = fmaf(n1, lo16(v1), a0); a1 = fmaf(n1, hi16(v1), a1);
        a0 = fmaf(n2, lo16(v2), a0); a1 = fmaf(n2, hi16(v2), a1);
        a0 = fmaf(n3, lo16(v3), a0); a1 = fmaf(n3, hi16(v3), a1);
        a0 = fmaf(n4, lo16(v4), a0); a1 = fmaf(n4, hi16(v4), a1);
        a0 = fmaf(n5, lo16(v5), a0); a1 = fmaf(n5, hi16(v5), a1);
        a0 = fmaf(n6, lo16(v6), a0); a1 = fmaf(n6, hi16(v6), a1);
        a0 = fmaf(n7, lo16(v7), a0); a1 = fmaf(n7, hi16(v7), a1);
      }
      for (; k < m; k++) {
        unsigned v = XWb[(size_t)__shfl((int)ed.x, k) * 48 + lp];
        float nn = __shfl(pw, k);
        a0 = fmaf(nn, lo16(v), a0); a1 = fmaf(nn, hi16(v), a1);
      }
    }
    a0 *= d; a1 *= d;                                // hoisted dis[dst]
    {   // self-loop + bias
      unsigned v = XWb[(size_t)n * 48 + lp];
      float d2 = d * d;
      a0 = fmaf(d2, lo16(v), a0) + sb96[2 * lp];
      a1 = fmaf(d2, hi16(v), a1) + sb96[2 * lp + 1];
    }
    if (l < 48) sg2[ws][l] = make_float2(a0, a1);
    float hpj = 0.f;
    if (l < 32) { hpj = Hp[(size_t)n * 32 + l]; shp[ws][l] = hpj; }
    // z (half 0) and r (half 1) gates in parallel
    const unsigned* Wm = half ? sLr : sLz;
    const float* gsel = half ? (sgf + 32) : sgf;
    float val = half ? sLrb[j] : sLzb[j];
#pragma unroll
    for (int k2 = 0; k2 < 16; k2++) {                // gate-input rows 0..31
      unsigned wv = Wm[k2 * 32 + j];
      val = fmaf(gsel[2 * k2],     lo16(wv), val);
      val = fmaf(gsel[2 * k2 + 1], hi16(wv), val);
    }
#pragma unroll
    for (int k2 = 16; k2 < 32; k2++) {               // Hp rows 32..63
      unsigned wv = Wm[k2 * 32 + j];
      val = fmaf(shp[ws][2 * k2 - 32], lo16(wv), val);
      val = fmaf(shp[ws][2 * k2 - 31], hi16(wv), val);
    }
    float gate = 1.f / (1.f + __expf(-val));         // Z (half0) / R (half1)
    if (half) shr[ws][j] = shp[ws][j] * gate;
    // h-tilde pre-activation, split across halves
    float s = half ? 0.f : sLhb[j];
#pragma unroll
    for (int k2 = 0; k2 < 16; k2++) {
      int kk2 = half ? (k2 + 16) : k2;
      unsigned wv = sLh[kk2 * 32 + j];
      float x0 = half ? shr[ws][2 * k2]     : sgf[64 + 2 * k2];
      float x1 = half ? shr[ws][2 * k2 + 1] : sgf[64 + 2 * k2 + 1];
      s = fmaf(x0, lo16(wv), s);
      s = fmaf(x1, hi16(wv), s);
    }
    s += __shfl_xor(s, 32);
    if (!half) {
      float ht = tanhf(s);
      float h = gate * hpj + (1.f - gate) * ht;
      outH[(size_t)n * 32 + j] = h;
      float cacc = fmaxf(h, 0.f) * shW[j];
#pragma unroll
      for (int off = 16; off > 0; off >>= 1) cacc += __shfl_xor(cacc, off, 32);
      if (j == 0) outY[n] = cacc + shb;
    }
  }
}

// ---------------------------------------------------------------------------
extern "C" void kernel_launch(void* const* d_in, const int* in_sizes, int n_in,
                              void* d_out, int out_size, void* d_ws, size_t ws_size,
                              hipStream_t stream) {
  const float* x    = (const float*)d_in[0];
  const int*   ei   = (const int*)d_in[1];
  const float* w    = (const float*)d_in[2];
  const float* Hp   = (const float*)d_in[3];
  const float* Wz   = (const float*)d_in[4];
  const float* bz   = (const float*)d_in[5];
  const float* Wr   = (const float*)d_in[6];
  const float* br   = (const float*)d_in[7];
  const float* Wh   = (const float*)d_in[8];
  const float* bh   = (const float*)d_in[9];
  const float* LzW  = (const float*)d_in[10];
  const float* Lzb  = (const float*)d_in[11];
  const float* LrW  = (const float*)d_in[12];
  const float* Lrb  = (const float*)d_in[13];
  const float* LhW  = (const float*)d_in[14];
  const float* Lhb  = (const float*)d_in[15];
  const float* hW   = (const float*)d_in[16];
  const float* hb   = (const float*)d_in[17];

  const int N = N_NODES;
  const int E = in_sizes[2];

  char* p = (char*)d_ws;
  unsigned* XWb   = (unsigned*)p;  p += (size_t)N * 48 * 4;   // 19.2 MB
  uint2*    e2    = (uint2*)p;     p += (size_t)E * 8;        // 25.6 MB
  unsigned* drank = (unsigned*)p;  p += (size_t)E * 4;        // 12.8 MB
  unsigned* cnt   = (unsigned*)p;  p += (size_t)N * 4;
  int* rowstart   = (int*)p;       p += (size_t)N * 4;
  float* dis      = (float*)p;     p += (size_t)N * 4;
  int* partials   = (int*)p;       p += 256 * 4;
  int* pOff       = (int*)p;

  float* outY = (float*)d_out;           // N
  float* outH = outY + N;                // N*32

  hipMemsetAsync(cnt, 0, (size_t)N * sizeof(unsigned), stream);

  const int nScanBlocks = (N + 511) / 512;   // 196

  gemm_histo<<<GEMM_BLOCKS + HISTO_BLOCKS, 256, 0, stream>>>(
      x, Wz, Wr, Wh, XWb, ei, cnt, drank, E);
  scan_block<<<nScanBlocks, 512, 0, stream>>>(cnt, rowstart, partials, N);
  scan_partials<<<1, 256, 0, stream>>>(partials, pOff, nScanBlocks);
  add_offsets<<<(N + 255) / 256, 256, 0, stream>>>(rowstart, pOff, N);
  edge_place<<<2048, 256, 0, stream>>>(ei, w, drank, rowstart, e2, E);
  deg_dis<<<2048, 256, 0, stream>>>(e2, rowstart, cnt, dis, N);
  gru_gather<<<2048, 256, 0, stream>>>(e2, rowstart, cnt, XWb, dis, Hp,
                                       bz, br, bh,
                                       LzW, Lzb, LrW, Lrb, LhW, Lhb,
                                       hW, hb, outY, outH, N);
}

// Round 5
// 403.194 us; speedup vs baseline: 3.3136x; 1.1264x over previous
//
#include <hip/hip_runtime.h>
#include <math.h>

#define N_NODES 100000
#define F_INDIM 256
#define GEMM_BLOCKS 3126             // 3-of-5 slots; last block bounds-checked
#define HISTO_BLOCKS 2084            // 2-of-5 slots
#define TOTAL_BLOCKS 5210            // 1042 groups of 5

// pack two f32 into bf16 pair (RNE), lo = a, hi = b
__device__ __forceinline__ unsigned bf16pack(float a, float b) {
  unsigned ua = __float_as_uint(a);
  ua += 0x7FFFu + ((ua >> 16) & 1u);
  unsigned ub = __float_as_uint(b);
  ub += 0x7FFFu + ((ub >> 16) & 1u);
  return (ub & 0xFFFF0000u) | (ua >> 16);
}
__device__ __forceinline__ float lo16(unsigned v) { return __uint_as_float(v << 16); }
__device__ __forceinline__ float hi16(unsigned v) { return __uint_as_float(v & 0xFFFF0000u); }

// ---------------------------------------------------------------------------
// Heterogeneous kernel, INTERLEAVED block types (blockIdx%5: 0,1=histo 2,3,4=GEMM)
// so the atomic stream starts at t=0 and GEMM VALU work hides under it.
// GEMM: XWb = x @ [Wz|Wr|Wh], bf16-pair packed (48 uints/row).
// Histo: drank[e] = (rank<<17)|dst via one returning atomic per edge, 4 in flight.
// ---------------------------------------------------------------------------
__global__ __launch_bounds__(256) void gemm_histo(
    const float* __restrict__ x,
    const float* __restrict__ Wz, const float* __restrict__ Wr, const float* __restrict__ Wh,
    unsigned* __restrict__ XWb,
    const int* __restrict__ ei, unsigned* __restrict__ cnt, unsigned* __restrict__ drank,
    int E) {
  __shared__ float xs[32][64];
  __shared__ float wsz[64][32];
  __shared__ float wsr[64][32];
  __shared__ float wsh[64][32];
  const int t = threadIdx.x;
  const int m = blockIdx.x % 5;
  if (m < 2) {
    // ---- histogram path ----
    const int hid = (blockIdx.x / 5) * 2 + m;
    const int stride = HISTO_BLOCKS * 256;
    int e = hid * 256 + t;
    for (; e + 3 * stride < E; e += 4 * stride) {
      int d0 = ei[E + e];
      int d1 = ei[E + e + stride];
      int d2 = ei[E + e + 2 * stride];
      int d3 = ei[E + e + 3 * stride];
      unsigned r0 = atomicAdd(&cnt[d0], 1u);
      unsigned r1 = atomicAdd(&cnt[d1], 1u);
      unsigned r2 = atomicAdd(&cnt[d2], 1u);
      unsigned r3 = atomicAdd(&cnt[d3], 1u);
      drank[e]              = (r0 << 17) | (unsigned)d0;
      drank[e + stride]     = (r1 << 17) | (unsigned)d1;
      drank[e + 2 * stride] = (r2 << 17) | (unsigned)d2;
      drank[e + 3 * stride] = (r3 << 17) | (unsigned)d3;
    }
    for (; e < E; e += stride) {
      int dst = ei[E + e];
      unsigned r = atomicAdd(&cnt[dst], 1u);
      drank[e] = (r << 17) | (unsigned)dst;
    }
    return;
  }
  // ---- GEMM path ----
  const int gid = (blockIdx.x / 5) * 3 + (m - 2);
  const int row0 = gid * 32;
  if (row0 >= N_NODES) return;
  const int cg = t & 31;
  const int rg = (t >> 5) * 4;
  float acc[4][3] = {};
  for (int k0 = 0; k0 < 256; k0 += 64) {
#pragma unroll
    for (int i = 0; i < 8; i++) {
      int l = t + 256 * i;
      int r = l >> 6, kk = l & 63;
      xs[r][kk] = x[(size_t)(row0 + r) * F_INDIM + k0 + kk];
    }
#pragma unroll
    for (int i = 0; i < 8; i++) {
      int l = t + 256 * i;
      int kk = l >> 5, c = l & 31;
      wsz[kk][c] = Wz[(k0 + kk) * 32 + c];
      wsr[kk][c] = Wr[(k0 + kk) * 32 + c];
      wsh[kk][c] = Wh[(k0 + kk) * 32 + c];
    }
    __syncthreads();
#pragma unroll 4
    for (int kk = 0; kk < 64; kk++) {
      float wz = wsz[kk][cg], wr = wsr[kk][cg], wh = wsh[kk][cg];
#pragma unroll
      for (int r = 0; r < 4; r++) {
        float xv = xs[rg + r][kk];
        acc[r][0] = fmaf(xv, wz, acc[r][0]);
        acc[r][1] = fmaf(xv, wr, acc[r][1]);
        acc[r][2] = fmaf(xv, wh, acc[r][2]);
      }
    }
    __syncthreads();
  }
#pragma unroll
  for (int r = 0; r < 4; r++) {
    int row = row0 + rg + r;
#pragma unroll
    for (int g2 = 0; g2 < 3; g2++) {
      float other = __shfl_xor(acc[r][g2], 1);
      if ((cg & 1) == 0)
        XWb[(size_t)row * 48 + g2 * 16 + (cg >> 1)] = bf16pack(acc[r][g2], other);
    }
  }
}

// ---------------------------------------------------------------------------
// Exclusive scan of cnt -> rowstart (block-local; pOff folded into consumers)
// ---------------------------------------------------------------------------
__global__ __launch_bounds__(512) void scan_block(const unsigned* __restrict__ cnt,
                                                  int* __restrict__ rowstart,
                                                  int* __restrict__ partials, int n) {
  __shared__ int s[512];
  int t = threadIdx.x, i = blockIdx.x * 512 + t;
  int v = (i < n) ? (int)cnt[i] : 0;
  s[t] = v;
  __syncthreads();
  for (int off = 1; off < 512; off <<= 1) {
    int xv = (t >= off) ? s[t - off] : 0;
    __syncthreads();
    s[t] += xv;
    __syncthreads();
  }
  if (i < n) rowstart[i] = s[t] - v;
  if (t == 511) partials[blockIdx.x] = s[511];
}

__global__ __launch_bounds__(256) void scan_partials(const int* __restrict__ partials,
                                                     int* __restrict__ pOff, int np) {
  __shared__ int s[256];
  int t = threadIdx.x;
  int v = (t < np) ? partials[t] : 0;
  s[t] = v;
  __syncthreads();
  for (int off = 1; off < 256; off <<= 1) {
    int xv = (t >= off) ? s[t - off] : 0;
    __syncthreads();
    s[t] += xv;
    __syncthreads();
  }
  if (t < np) pOff[t] = s[t] - v;
}

// ---------------------------------------------------------------------------
// Place edges into CSR buckets (no atomics): pos = rowstart[dst]+pOff[dst>>9]+rank
// ---------------------------------------------------------------------------
__global__ void edge_place(const int* __restrict__ ei, const float* __restrict__ w,
                           const unsigned* __restrict__ drank, const int* __restrict__ rowstart,
                           const int* __restrict__ pOff, uint2* __restrict__ e2, int E) {
  int stride = gridDim.x * blockDim.x;
  for (int e = blockIdx.x * blockDim.x + threadIdx.x; e < E; e += stride) {
    unsigned dr = drank[e];
    int dst = (int)(dr & 0x1FFFFu);
    int rank = (int)(dr >> 17);
    int pos = rowstart[dst] + pOff[dst >> 9] + rank;
    e2[pos] = make_uint2((unsigned)ei[e], __float_as_uint(w[e]));
  }
}

// ---------------------------------------------------------------------------
// deg/dis from CSR buckets: one wave per node, lanes stride the bucket.
// ---------------------------------------------------------------------------
__global__ __launch_bounds__(256) void deg_dis(const uint2* __restrict__ e2,
                                               const int* __restrict__ rowstart,
                                               const int* __restrict__ pOff,
                                               const unsigned* __restrict__ cnt,
                                               float* __restrict__ dis, int N) {
  int wid = (blockIdx.x * blockDim.x + threadIdx.x) >> 6;
  int nw = (gridDim.x * blockDim.x) >> 6;
  int l = threadIdx.x & 63;
  for (int n = wid; n < N; n += nw) {
    int start = rowstart[n] + pOff[n >> 9], c = (int)cnt[n];
    float s = 0.f;
    for (int i = l; i < c; i += 64) s += __uint_as_float(e2[start + i].y);
#pragma unroll
    for (int off = 32; off > 0; off >>= 1) s += __shfl_xor(s, off);
    if (l == 0) dis[n] = rsqrtf(s + 1.0f);
  }
}

// ---------------------------------------------------------------------------
// Fused gather + GRU + head. One wave64 per node, 8-wide load MLP, bf16 LDS
// weights, launch_bounds(256,6).
// ---------------------------------------------------------------------------
__global__ __launch_bounds__(256, 6) void gru_gather(
    const uint2* __restrict__ e2, const int* __restrict__ rowstart,
    const int* __restrict__ pOff,
    const unsigned* __restrict__ cnt, const unsigned* __restrict__ XWb,
    const float* __restrict__ dis, const float* __restrict__ Hp,
    const float* __restrict__ bz, const float* __restrict__ br, const float* __restrict__ bh,
    const float* __restrict__ LzW, const float* __restrict__ Lzb,
    const float* __restrict__ LrW, const float* __restrict__ Lrb,
    const float* __restrict__ LhW, const float* __restrict__ Lhb,
    const float* __restrict__ hW, const float* __restrict__ hb,
    float* __restrict__ outY, float* __restrict__ outH, int N) {
  __shared__ unsigned sLz[1024], sLr[1024], sLh[1024];   // bf16-pair packed, 12 KB
  __shared__ float sb96[96];
  __shared__ float sLzb[32], sLrb[32], sLhb[32], shW[32];
  __shared__ float2 sg2[4][48];
  __shared__ float shp[4][32], shr[4][32];
  __shared__ float shb;
  const int t = threadIdx.x;
  for (int i = t; i < 1024; i += 256) {
    int jj = i & 31, k2 = i >> 5;
    sLz[i] = bf16pack(LzW[(2 * k2) * 32 + jj], LzW[(2 * k2 + 1) * 32 + jj]);
    sLr[i] = bf16pack(LrW[(2 * k2) * 32 + jj], LrW[(2 * k2 + 1) * 32 + jj]);
    sLh[i] = bf16pack(LhW[(2 * k2) * 32 + jj], LhW[(2 * k2 + 1) * 32 + jj]);
  }
  if (t < 32) {
    sb96[t] = bz[t]; sb96[32 + t] = br[t]; sb96[64 + t] = bh[t];
    sLzb[t] = Lzb[t]; sLrb[t] = Lrb[t]; sLhb[t] = Lhb[t]; shW[t] = hW[t];
  }
  if (t == 0) shb = hb[0];
  __syncthreads();
  const int ws = t >> 6;
  const int l = t & 63;
  const int lp = (l < 48) ? l : 47;
  const int j = l & 31;
  const int half = l >> 5;
  const float* sgf = (const float*)&sg2[ws][0];
  int wid = blockIdx.x * 4 + ws;
  int nw = gridDim.x * 4;
  for (int n = wid; n < N; n += nw) {
    const int start = rowstart[n] + pOff[n >> 9];
    const int c = (int)cnt[n];
    const float d = dis[n];
    float a0 = 0.f, a1 = 0.f;
    for (int e0 = 0; e0 < c; e0 += 64) {
      uint2 ed = make_uint2(0u, 0u);
      float pw = 0.f;
      if (e0 + l < c) {
        ed = e2[start + e0 + l];
        pw = __uint_as_float(ed.y) * dis[ed.x];      // w * dis[src]
      }
      int m = c - e0; if (m > 64) m = 64;
      int k = 0;
      for (; k + 8 <= m; k += 8) {                   // 8 loads in flight
        unsigned v0 = XWb[(size_t)__shfl((int)ed.x, k + 0) * 48 + lp];
        unsigned v1 = XWb[(size_t)__shfl((int)ed.x, k + 1) * 48 + lp];
        unsigned v2 = XWb[(size_t)__shfl((int)ed.x, k + 2) * 48 + lp];
        unsigned v3 = XWb[(size_t)__shfl((int)ed.x, k + 3) * 48 + lp];
        unsigned v4 = XWb[(size_t)__shfl((int)ed.x, k + 4) * 48 + lp];
        unsigned v5 = XWb[(size_t)__shfl((int)ed.x, k + 5) * 48 + lp];
        unsigned v6 = XWb[(size_t)__shfl((int)ed.x, k + 6) * 48 + lp];
        unsigned v7 = XWb[(size_t)__shfl((int)ed.x, k + 7) * 48 + lp];
        float n0 = __shfl(pw, k + 0), n1 = __shfl(pw, k + 1);
        float n2 = __shfl(pw, k + 2), n3 = __shfl(pw, k + 3);
        float n4 = __shfl(pw, k + 4), n5 = __shfl(pw, k + 5);
        float n6 = __shfl(pw, k + 6), n7 = __shfl(pw, k + 7);
        a0 = fmaf(n0, lo16(v0), a0); a1 = fmaf(n0, hi16(v0), a1);
        a0 = fmaf(n1, lo16(v1), a0); a1 = fmaf(n1, hi16(v1), a1);
        a0 = fmaf(n2, lo16(v2), a0); a1 = fmaf(n2, hi16(v2), a1);
        a0 = fmaf(n3, lo16(v3), a0); a1 = fmaf(n3, hi16(v3), a1);
        a0 = fmaf(n4, lo16(v4), a0); a1 = fmaf(n4, hi16(v4), a1);
        a0 = fmaf(n5, lo16(v5), a0); a1 = fmaf(n5, hi16(v5), a1);
        a0 = fmaf(n6, lo16(v6), a0); a1 = fmaf(n6, hi16(v6), a1);
        a0 = fmaf(n7, lo16(v7), a0); a1 = fmaf(n7, hi16(v7), a1);
      }
      for (; k < m; k++) {
        unsigned v = XWb[(size_t)__shfl((int)ed.x, k) * 48 + lp];
        float nn = __shfl(pw, k);
        a0 = fmaf(nn, lo16(v), a0); a1 = fmaf(nn, hi16(v), a1);
      }
    }
    a0 *= d; a1 *= d;
    {   // self-loop + bias
      unsigned v = XWb[(size_t)n * 48 + lp];
      float d2 = d * d;
      a0 = fmaf(d2, lo16(v), a0) + sb96[2 * lp];
      a1 = fmaf(d2, hi16(v), a1) + sb96[2 * lp + 1];
    }
    if (l < 48) sg2[ws][l] = make_float2(a0, a1);
    float hpj = 0.f;
    if (l < 32) { hpj = Hp[(size_t)n * 32 + l]; shp[ws][l] = hpj; }
    const unsigned* Wm = half ? sLr : sLz;
    const float* gsel = half ? (sgf + 32) : sgf;
    float val = half ? sLrb[j] : sLzb[j];
#pragma unroll
    for (int k2 = 0; k2 < 16; k2++) {
      unsigned wv = Wm[k2 * 32 + j];
      val = fmaf(gsel[2 * k2],     lo16(wv), val);
      val = fmaf(gsel[2 * k2 + 1], hi16(wv), val);
    }
#pragma unroll
    for (int k2 = 16; k2 < 32; k2++) {
      unsigned wv = Wm[k2 * 32 + j];
      val = fmaf(shp[ws][2 * k2 - 32], lo16(wv), val);
      val = fmaf(shp[ws][2 * k2 - 31], hi16(wv), val);
    }
    float gate = 1.f / (1.f + __expf(-val));
    if (half) shr[ws][j] = shp[ws][j] * gate;
    float s = half ? 0.f : sLhb[j];
#pragma unroll
    for (int k2 = 0; k2 < 16; k2++) {
      int kk2 = half ? (k2 + 16) : k2;
      unsigned wv = sLh[kk2 * 32 + j];
      float x0 = half ? shr[ws][2 * k2]     : sgf[64 + 2 * k2];
      float x1 = half ? shr[ws][2 * k2 + 1] : sgf[64 + 2 * k2 + 1];
      s = fmaf(x0, lo16(wv), s);
      s = fmaf(x1, hi16(wv), s);
    }
    s += __shfl_xor(s, 32);
    if (!half) {
      float ht = tanhf(s);
      float h = gate * hpj + (1.f - gate) * ht;
      outH[(size_t)n * 32 + j] = h;
      float cacc = fmaxf(h, 0.f) * shW[j];
#pragma unroll
      for (int off = 16; off > 0; off >>= 1) cacc += __shfl_xor(cacc, off, 32);
      if (j == 0) outY[n] = cacc + shb;
    }
  }
}

// ---------------------------------------------------------------------------
extern "C" void kernel_launch(void* const* d_in, const int* in_sizes, int n_in,
                              void* d_out, int out_size, void* d_ws, size_t ws_size,
                              hipStream_t stream) {
  const float* x    = (const float*)d_in[0];
  const int*   ei   = (const int*)d_in[1];
  const float* w    = (const float*)d_in[2];
  const float* Hp   = (const float*)d_in[3];
  const float* Wz   = (const float*)d_in[4];
  const float* bz   = (const float*)d_in[5];
  const float* Wr   = (const float*)d_in[6];
  const float* br   = (const float*)d_in[7];
  const float* Wh   = (const float*)d_in[8];
  const float* bh   = (const float*)d_in[9];
  const float* LzW  = (const float*)d_in[10];
  const float* Lzb  = (const float*)d_in[11];
  const float* LrW  = (const float*)d_in[12];
  const float* Lrb  = (const float*)d_in[13];
  const float* LhW  = (const float*)d_in[14];
  const float* Lhb  = (const float*)d_in[15];
  const float* hW   = (const float*)d_in[16];
  const float* hb   = (const float*)d_in[17];

  const int N = N_NODES;
  const int E = in_sizes[2];

  char* p = (char*)d_ws;
  unsigned* XWb   = (unsigned*)p;  p += (size_t)N * 48 * 4;   // 19.2 MB
  uint2*    e2    = (uint2*)p;     p += (size_t)E * 8;        // 25.6 MB
  unsigned* drank = (unsigned*)p;  p += (size_t)E * 4;        // 12.8 MB
  unsigned* cnt   = (unsigned*)p;  p += (size_t)N * 4;
  int* rowstart   = (int*)p;       p += (size_t)N * 4;
  float* dis      = (float*)p;     p += (size_t)N * 4;
  int* partials   = (int*)p;       p += 256 * 4;
  int* pOff       = (int*)p;

  float* outY = (float*)d_out;           // N
  float* outH = outY + N;                // N*32

  hipMemsetAsync(cnt, 0, (size_t)N * sizeof(unsigned), stream);

  const int nScanBlocks = (N + 511) / 512;   // 196

  gemm_histo<<<TOTAL_BLOCKS, 256, 0, stream>>>(
      x, Wz, Wr, Wh, XWb, ei, cnt, drank, E);
  scan_block<<<nScanBlocks, 512, 0, stream>>>(cnt, rowstart, partials, N);
  scan_partials<<<1, 256, 0, stream>>>(partials, pOff, nScanBlocks);
  edge_place<<<2048, 256, 0, stream>>>(ei, w, drank, rowstart, pOff, e2, E);
  deg_dis<<<2048, 256, 0, stream>>>(e2, rowstart, pOff, cnt, dis, N);
  gru_gather<<<2048, 256, 0, stream>>>(e2, rowstart, pOff, cnt, XWb, dis, Hp,
                                       bz, br, bh,
                                       LzW, Lzb, LrW, Lrb, LhW, Lhb,
                                       hW, hb, outY, outH, N);
}

// Round 6
// 346.248 us; speedup vs baseline: 3.8586x; 1.1645x over previous
//
#include <hip/hip_runtime.h>
#include <math.h>

#define N_NODES 100000
#define F_INDIM 256
#define GEMM_BLOCKS 3126             // 3-of-5 slots; last block bounds-checked
#define HISTO_BLOCKS 2084            // 2-of-5 slots
#define TOTAL_BLOCKS 5210            // 1042 groups of 5

// pack two f32 into bf16 pair (RNE), lo = a, hi = b
__device__ __forceinline__ unsigned bf16pack(float a, float b) {
  unsigned ua = __float_as_uint(a);
  ua += 0x7FFFu + ((ua >> 16) & 1u);
  unsigned ub = __float_as_uint(b);
  ub += 0x7FFFu + ((ub >> 16) & 1u);
  return (ub & 0xFFFF0000u) | (ua >> 16);
}
__device__ __forceinline__ float lo16(unsigned v) { return __uint_as_float(v << 16); }
__device__ __forceinline__ float hi16(unsigned v) { return __uint_as_float(v & 0xFFFF0000u); }

// ---------------------------------------------------------------------------
// Heterogeneous kernel, INTERLEAVED block types (blockIdx%5: 0,1=histo 2,3,4=GEMM)
// ---------------------------------------------------------------------------
__global__ __launch_bounds__(256) void gemm_histo(
    const float* __restrict__ x,
    const float* __restrict__ Wz, const float* __restrict__ Wr, const float* __restrict__ Wh,
    unsigned* __restrict__ XWb,
    const int* __restrict__ ei, unsigned* __restrict__ cnt, unsigned* __restrict__ drank,
    int E) {
  __shared__ float xs[32][64];
  __shared__ float wsz[64][32];
  __shared__ float wsr[64][32];
  __shared__ float wsh[64][32];
  const int t = threadIdx.x;
  const int m = blockIdx.x % 5;
  if (m < 2) {
    // ---- histogram path ----
    const int hid = (blockIdx.x / 5) * 2 + m;
    const int stride = HISTO_BLOCKS * 256;
    int e = hid * 256 + t;
    for (; e + 3 * stride < E; e += 4 * stride) {
      int d0 = ei[E + e];
      int d1 = ei[E + e + stride];
      int d2 = ei[E + e + 2 * stride];
      int d3 = ei[E + e + 3 * stride];
      unsigned r0 = atomicAdd(&cnt[d0], 1u);
      unsigned r1 = atomicAdd(&cnt[d1], 1u);
      unsigned r2 = atomicAdd(&cnt[d2], 1u);
      unsigned r3 = atomicAdd(&cnt[d3], 1u);
      drank[e]              = (r0 << 17) | (unsigned)d0;
      drank[e + stride]     = (r1 << 17) | (unsigned)d1;
      drank[e + 2 * stride] = (r2 << 17) | (unsigned)d2;
      drank[e + 3 * stride] = (r3 << 17) | (unsigned)d3;
    }
    for (; e < E; e += stride) {
      int dst = ei[E + e];
      unsigned r = atomicAdd(&cnt[dst], 1u);
      drank[e] = (r << 17) | (unsigned)dst;
    }
    return;
  }
  // ---- GEMM path ----
  const int gid = (blockIdx.x / 5) * 3 + (m - 2);
  const int row0 = gid * 32;
  if (row0 >= N_NODES) return;
  const int cg = t & 31;
  const int rg = (t >> 5) * 4;
  float acc[4][3] = {};
  for (int k0 = 0; k0 < 256; k0 += 64) {
#pragma unroll
    for (int i = 0; i < 8; i++) {
      int l = t + 256 * i;
      int r = l >> 6, kk = l & 63;
      xs[r][kk] = x[(size_t)(row0 + r) * F_INDIM + k0 + kk];
    }
#pragma unroll
    for (int i = 0; i < 8; i++) {
      int l = t + 256 * i;
      int kk = l >> 5, c = l & 31;
      wsz[kk][c] = Wz[(k0 + kk) * 32 + c];
      wsr[kk][c] = Wr[(k0 + kk) * 32 + c];
      wsh[kk][c] = Wh[(k0 + kk) * 32 + c];
    }
    __syncthreads();
#pragma unroll 4
    for (int kk = 0; kk < 64; kk++) {
      float wz = wsz[kk][cg], wr = wsr[kk][cg], wh = wsh[kk][cg];
#pragma unroll
      for (int r = 0; r < 4; r++) {
        float xv = xs[rg + r][kk];
        acc[r][0] = fmaf(xv, wz, acc[r][0]);
        acc[r][1] = fmaf(xv, wr, acc[r][1]);
        acc[r][2] = fmaf(xv, wh, acc[r][2]);
      }
    }
    __syncthreads();
  }
#pragma unroll
  for (int r = 0; r < 4; r++) {
    int row = row0 + rg + r;
#pragma unroll
    for (int g2 = 0; g2 < 3; g2++) {
      float other = __shfl_xor(acc[r][g2], 1);
      if ((cg & 1) == 0)
        XWb[(size_t)row * 48 + g2 * 16 + (cg >> 1)] = bf16pack(acc[r][g2], other);
    }
  }
}

// ---------------------------------------------------------------------------
// Exclusive scan of cnt -> rowstart (block-local; pOff folded into consumers)
// ---------------------------------------------------------------------------
__global__ __launch_bounds__(512) void scan_block(const unsigned* __restrict__ cnt,
                                                  int* __restrict__ rowstart,
                                                  int* __restrict__ partials, int n) {
  __shared__ int s[512];
  int t = threadIdx.x, i = blockIdx.x * 512 + t;
  int v = (i < n) ? (int)cnt[i] : 0;
  s[t] = v;
  __syncthreads();
  for (int off = 1; off < 512; off <<= 1) {
    int xv = (t >= off) ? s[t - off] : 0;
    __syncthreads();
    s[t] += xv;
    __syncthreads();
  }
  if (i < n) rowstart[i] = s[t] - v;
  if (t == 511) partials[blockIdx.x] = s[511];
}

__global__ __launch_bounds__(256) void scan_partials(const int* __restrict__ partials,
                                                     int* __restrict__ pOff, int np) {
  __shared__ int s[256];
  int t = threadIdx.x;
  int v = (t < np) ? partials[t] : 0;
  s[t] = v;
  __syncthreads();
  for (int off = 1; off < 256; off <<= 1) {
    int xv = (t >= off) ? s[t - off] : 0;
    __syncthreads();
    s[t] += xv;
    __syncthreads();
  }
  if (t < np) pOff[t] = s[t] - v;
}

// ---------------------------------------------------------------------------
// Place edges into CSR buckets (no atomics): pos = rowstart[dst]+pOff[dst>>9]+rank
// ---------------------------------------------------------------------------
__global__ void edge_place(const int* __restrict__ ei, const float* __restrict__ w,
                           const unsigned* __restrict__ drank, const int* __restrict__ rowstart,
                           const int* __restrict__ pOff, uint2* __restrict__ e2, int E) {
  int stride = gridDim.x * blockDim.x;
  for (int e = blockIdx.x * blockDim.x + threadIdx.x; e < E; e += stride) {
    unsigned dr = drank[e];
    int dst = (int)(dr & 0x1FFFFu);
    int rank = (int)(dr >> 17);
    int pos = rowstart[dst] + pOff[dst >> 9] + rank;
    e2[pos] = make_uint2((unsigned)ei[e], __float_as_uint(w[e]));
  }
}

// ---------------------------------------------------------------------------
// deg/dis from CSR buckets: one wave per node, lanes stride the bucket.
// ---------------------------------------------------------------------------
__global__ __launch_bounds__(256) void deg_dis(const uint2* __restrict__ e2,
                                               const int* __restrict__ rowstart,
                                               const int* __restrict__ pOff,
                                               const unsigned* __restrict__ cnt,
                                               float* __restrict__ dis, int N) {
  int wid = (blockIdx.x * blockDim.x + threadIdx.x) >> 6;
  int nw = (gridDim.x * blockDim.x) >> 6;
  int l = threadIdx.x & 63;
  for (int n = wid; n < N; n += nw) {
    int start = rowstart[n] + pOff[n >> 9], c = (int)cnt[n];
    float s = 0.f;
    for (int i = l; i < c; i += 64) s += __uint_as_float(e2[start + i].y);
#pragma unroll
    for (int off = 32; off > 0; off >>= 1) s += __shfl_xor(s, off);
    if (l == 0) dis[n] = rsqrtf(s + 1.0f);
  }
}

// ---------------------------------------------------------------------------
// Fused gather + GRU + head. One wave64 per node. Gather: 5 edges per wave-
// load — lane l -> (slot s=l/12, quarter q=l%12), each lane loads dwordx4
// (8 bf16 feats) of its slot's src row. One bpermute pair per 5 edges.
// 8 f32 accumulators/lane; 5-slot reduce via per-wave LDS scratch.
// ---------------------------------------------------------------------------
#define FMA8(vv, nn)                                              \
  a0 = fmaf(nn, lo16(vv.x), a0); a1 = fmaf(nn, hi16(vv.x), a1);   \
  a2 = fmaf(nn, lo16(vv.y), a2); a3 = fmaf(nn, hi16(vv.y), a3);   \
  a4 = fmaf(nn, lo16(vv.z), a4); a5 = fmaf(nn, hi16(vv.z), a5);   \
  a6 = fmaf(nn, lo16(vv.w), a6); a7 = fmaf(nn, hi16(vv.w), a7);

__global__ __launch_bounds__(256, 6) void gru_gather(
    const uint2* __restrict__ e2, const int* __restrict__ rowstart,
    const int* __restrict__ pOff,
    const unsigned* __restrict__ cnt, const unsigned* __restrict__ XWb,
    const float* __restrict__ dis, const float* __restrict__ Hp,
    const float* __restrict__ bz, const float* __restrict__ br, const float* __restrict__ bh,
    const float* __restrict__ LzW, const float* __restrict__ Lzb,
    const float* __restrict__ LrW, const float* __restrict__ Lrb,
    const float* __restrict__ LhW, const float* __restrict__ Lhb,
    const float* __restrict__ hW, const float* __restrict__ hb,
    float* __restrict__ outY, float* __restrict__ outH, int N) {
  __shared__ unsigned sLz[1024], sLr[1024], sLh[1024];   // bf16-pair packed, 12 KB
  __shared__ float aggTmp[4][5][96];                     // per-wave slot partials, 7.7 KB
  __shared__ float sb96[96];
  __shared__ float sLzb[32], sLrb[32], sLhb[32], shW[32];
  __shared__ float2 sg2[4][48];
  __shared__ float shp[4][32], shr[4][32];
  __shared__ float shb;
  const int t = threadIdx.x;
  for (int i = t; i < 1024; i += 256) {
    int jj = i & 31, k2 = i >> 5;
    sLz[i] = bf16pack(LzW[(2 * k2) * 32 + jj], LzW[(2 * k2 + 1) * 32 + jj]);
    sLr[i] = bf16pack(LrW[(2 * k2) * 32 + jj], LrW[(2 * k2 + 1) * 32 + jj]);
    sLh[i] = bf16pack(LhW[(2 * k2) * 32 + jj], LhW[(2 * k2 + 1) * 32 + jj]);
  }
  if (t < 32) {
    sb96[t] = bz[t]; sb96[32 + t] = br[t]; sb96[64 + t] = bh[t];
    sLzb[t] = Lzb[t]; sLrb[t] = Lrb[t]; sLhb[t] = Lhb[t]; shW[t] = hW[t];
  }
  if (t == 0) shb = hb[0];
  __syncthreads();
  const int ws = t >> 6;
  const int l = t & 63;
  const int lp = (l < 48) ? l : 47;
  const int j = l & 31;
  const int half = l >> 5;
  const int sl = (l < 60) ? (l / 12) : 4;     // slot 0..4
  const int q  = (l < 60) ? (l % 12) : 11;    // dword-quad within row
  const float* sgf = (const float*)&sg2[ws][0];
  int wid = blockIdx.x * 4 + ws;
  int nw = gridDim.x * 4;
  for (int n = wid; n < N; n += nw) {
    const int start = rowstart[n] + pOff[n >> 9];
    const int c = (int)cnt[n];
    const float d = dis[n];
    float a0 = 0.f, a1 = 0.f, a2 = 0.f, a3 = 0.f;
    float a4 = 0.f, a5 = 0.f, a6 = 0.f, a7 = 0.f;
    for (int e0 = 0; e0 < c; e0 += 60) {
      int srcv = 0; float pw = 0.f;
      if (l < 60 && e0 + l < c) {
        uint2 ed = e2[start + e0 + l];
        srcv = (int)ed.x;
        pw = __uint_as_float(ed.y) * dis[srcv];      // w * dis[src]
      }
      int mm = c - e0; if (mm > 60) mm = 60;
      for (int k0 = 0; k0 < mm; k0 += 10) {          // 2 macro-iters: 10 edges
        int iA = k0 + sl, iB = k0 + 5 + sl;          // iB <= 59 always
        int sA = __shfl(srcv, iA), sB = __shfl(srcv, iB);
        float nA = __shfl(pw, iA), nB = __shfl(pw, iB);   // 0 beyond mm
        uint4 vA = *(const uint4*)(XWb + sA * 48 + (q << 2));
        uint4 vB = *(const uint4*)(XWb + sB * 48 + (q << 2));
        FMA8(vA, nA);
        FMA8(vB, nB);
      }
    }
    // slot partials -> per-wave LDS scratch (lanes 60-63 excluded: duplicates)
    if (l < 60) {
      float4* dst4 = (float4*)&aggTmp[ws][sl][q * 8];
      dst4[0] = make_float4(a0, a1, a2, a3);
      dst4[1] = make_float4(a4, a5, a6, a7);
    }
    // reduce 5 slots: lane lp owns feature pair (2lp, 2lp+1)
    float g0 = 0.f, g1 = 0.f;
#pragma unroll
    for (int ss = 0; ss < 5; ss++) {
      float2 v2 = *(const float2*)&aggTmp[ws][ss][2 * lp];
      g0 += v2.x; g1 += v2.y;
    }
    g0 *= d; g1 *= d;                                // dis[dst] hoisted
    {   // self-loop + bias
      unsigned v = XWb[n * 48 + lp];
      float d2 = d * d;
      g0 = fmaf(d2, lo16(v), g0) + sb96[2 * lp];
      g1 = fmaf(d2, hi16(v), g1) + sb96[2 * lp + 1];
    }
    if (l < 48) sg2[ws][l] = make_float2(g0, g1);
    float hpj = 0.f;
    if (l < 32) { hpj = Hp[(size_t)n * 32 + l]; shp[ws][l] = hpj; }
    const unsigned* Wm = half ? sLr : sLz;
    const float* gsel = half ? (sgf + 32) : sgf;
    float val = half ? sLrb[j] : sLzb[j];
#pragma unroll
    for (int k2 = 0; k2 < 16; k2++) {
      unsigned wv = Wm[k2 * 32 + j];
      val = fmaf(gsel[2 * k2],     lo16(wv), val);
      val = fmaf(gsel[2 * k2 + 1], hi16(wv), val);
    }
#pragma unroll
    for (int k2 = 16; k2 < 32; k2++) {
      unsigned wv = Wm[k2 * 32 + j];
      val = fmaf(shp[ws][2 * k2 - 32], lo16(wv), val);
      val = fmaf(shp[ws][2 * k2 - 31], hi16(wv), val);
    }
    float gate = 1.f / (1.f + __expf(-val));
    if (half) shr[ws][j] = shp[ws][j] * gate;
    float s = half ? 0.f : sLhb[j];
#pragma unroll
    for (int k2 = 0; k2 < 16; k2++) {
      int kk2 = half ? (k2 + 16) : k2;
      unsigned wv = sLh[kk2 * 32 + j];
      float x0 = half ? shr[ws][2 * k2]     : sgf[64 + 2 * k2];
      float x1 = half ? shr[ws][2 * k2 + 1] : sgf[64 + 2 * k2 + 1];
      s = fmaf(x0, lo16(wv), s);
      s = fmaf(x1, hi16(wv), s);
    }
    s += __shfl_xor(s, 32);
    if (!half) {
      float ht = tanhf(s);
      float h = gate * hpj + (1.f - gate) * ht;
      outH[(size_t)n * 32 + j] = h;
      float cacc = fmaxf(h, 0.f) * shW[j];
#pragma unroll
      for (int off = 16; off > 0; off >>= 1) cacc += __shfl_xor(cacc, off, 32);
      if (j == 0) outY[n] = cacc + shb;
    }
  }
}

// ---------------------------------------------------------------------------
extern "C" void kernel_launch(void* const* d_in, const int* in_sizes, int n_in,
                              void* d_out, int out_size, void* d_ws, size_t ws_size,
                              hipStream_t stream) {
  const float* x    = (const float*)d_in[0];
  const int*   ei   = (const int*)d_in[1];
  const float* w    = (const float*)d_in[2];
  const float* Hp   = (const float*)d_in[3];
  const float* Wz   = (const float*)d_in[4];
  const float* bz   = (const float*)d_in[5];
  const float* Wr   = (const float*)d_in[6];
  const float* br   = (const float*)d_in[7];
  const float* Wh   = (const float*)d_in[8];
  const float* bh   = (const float*)d_in[9];
  const float* LzW  = (const float*)d_in[10];
  const float* Lzb  = (const float*)d_in[11];
  const float* LrW  = (const float*)d_in[12];
  const float* Lrb  = (const float*)d_in[13];
  const float* LhW  = (const float*)d_in[14];
  const float* Lhb  = (const float*)d_in[15];
  const float* hW   = (const float*)d_in[16];
  const float* hb   = (const float*)d_in[17];

  const int N = N_NODES;
  const int E = in_sizes[2];

  char* p = (char*)d_ws;
  unsigned* XWb   = (unsigned*)p;  p += (size_t)(N * 48 + 64) * 4;  // 19.2 MB (+pad)
  uint2*    e2    = (uint2*)p;     p += (size_t)E * 8;              // 25.6 MB
  unsigned* drank = (unsigned*)p;  p += (size_t)E * 4;              // 12.8 MB
  unsigned* cnt   = (unsigned*)p;  p += (size_t)N * 4;
  int* rowstart   = (int*)p;       p += (size_t)N * 4;
  float* dis      = (float*)p;     p += (size_t)N * 4;
  int* partials   = (int*)p;       p += 256 * 4;
  int* pOff       = (int*)p;

  float* outY = (float*)d_out;           // N
  float* outH = outY + N;                // N*32

  hipMemsetAsync(cnt, 0, (size_t)N * sizeof(unsigned), stream);

  const int nScanBlocks = (N + 511) / 512;   // 196

  gemm_histo<<<TOTAL_BLOCKS, 256, 0, stream>>>(
      x, Wz, Wr, Wh, XWb, ei, cnt, drank, E);
  scan_block<<<nScanBlocks, 512, 0, stream>>>(cnt, rowstart, partials, N);
  scan_partials<<<1, 256, 0, stream>>>(partials, pOff, nScanBlocks);
  edge_place<<<2048, 256, 0, stream>>>(ei, w, drank, rowstart, pOff, e2, E);
  deg_dis<<<2048, 256, 0, stream>>>(e2, rowstart, pOff, cnt, dis, N);
  gru_gather<<<1536, 256, 0, stream>>>(e2, rowstart, pOff, cnt, XWb, dis, Hp,
                                       bz, br, bh,
                                       LzW, Lzb, LrW, Lrb, LhW, Lhb,
                                       hW, hb, outY, outH, N);
}

// Round 7
// 283.640 us; speedup vs baseline: 4.7104x; 1.2207x over previous
//
#include <hip/hip_runtime.h>
#include <math.h>

#define N_NODES 100000
#define F_INDIM 256
#define NB 391            // coarse buckets: dst>>8, ceil(100000/256)
#define BCAP 9216         // bucket capacity: mean 8192 edges + 11 sigma
#define CNT_BLOCKS 521    // 1-of-7 slots
#define K1_BLOCKS 3647    // 521 bin + 3126 gemm (last gemm tile guarded)

// pack two f32 into bf16 pair (RNE), lo = a, hi = b
__device__ __forceinline__ unsigned bf16pack(float a, float b) {
  unsigned ua = __float_as_uint(a);
  ua += 0x7FFFu + ((ua >> 16) & 1u);
  unsigned ub = __float_as_uint(b);
  ub += 0x7FFFu + ((ub >> 16) & 1u);
  return (ub & 0xFFFF0000u) | (ua >> 16);
}
__device__ __forceinline__ float lo16(unsigned v) { return __uint_as_float(v << 16); }
__device__ __forceinline__ float hi16(unsigned v) { return __uint_as_float(v & 0xFFFF0000u); }

// ---------------------------------------------------------------------------
// Heterogeneous: blockIdx%7==0 -> edge binning (block-aggregated, LDS ranks,
// ONE global atomic per (block,coarse-bin)); else -> f32 GEMM tile of
// XWb = x @ [Wz|Wr|Wh] (bf16-pair packed, 48 uints/row).
// Bin block: two rounds over its 6144-edge tile:
//   round1: LDS count per coarse bin -> reserve [atomicAdd(cursor[bin], c)]
//   round2: LDS rank -> staged[bin*BCAP + base + rank] = (src|dstLow<<17, w)
// ---------------------------------------------------------------------------
__global__ __launch_bounds__(256) void gemm_bin(
    const float* __restrict__ x,
    const float* __restrict__ Wz, const float* __restrict__ Wr, const float* __restrict__ Wh,
    unsigned* __restrict__ XWb,
    const int* __restrict__ ei, const float* __restrict__ w,
    int* __restrict__ bucketCursor, uint2* __restrict__ staged, int E) {
  __shared__ float smem[8192];   // 32 KB, overlaid between the two roles
  const int t = threadIdx.x;
  const int m = blockIdx.x % 7;
  if (m == 0) {
    // ---- binning role ----
    int* lc    = (int*)smem;          // [NB] counts / rank cursors
    int* lbase = (int*)smem + 512;    // [NB] reserved base within bucket
    for (int i = t; i < NB; i += 256) lc[i] = 0;
    __syncthreads();
    const int base = (blockIdx.x / 7) * 6144;
#pragma unroll
    for (int i = 0; i < 24; i++) {
      int e = base + i * 256 + t;
      if (e < E) atomicAdd(&lc[((unsigned)ei[E + e]) >> 8], 1);
    }
    __syncthreads();
    for (int i = t; i < NB; i += 256) {
      int c = lc[i];
      lbase[i] = c ? atomicAdd(&bucketCursor[i], c) : 0;
    }
    __syncthreads();
    for (int i = t; i < NB; i += 256) lc[i] = 0;
    __syncthreads();
#pragma unroll
    for (int i = 0; i < 24; i++) {
      int e = base + i * 256 + t;
      if (e < E) {
        unsigned dst = (unsigned)ei[E + e];
        int b = dst >> 8;
        int r = lbase[b] + atomicAdd(&lc[b], 1);
        if (r < BCAP)
          staged[(size_t)b * BCAP + r] =
              make_uint2((unsigned)ei[e] | ((dst & 255u) << 17), __float_as_uint(w[e]));
      }
    }
    return;
  }
  // ---- GEMM role ----
  float (*xs)[64]  = (float(*)[64])smem;            // 32x64
  float (*wsz)[32] = (float(*)[32])(smem + 2048);   // 64x32
  float (*wsr)[32] = (float(*)[32])(smem + 4096);
  float (*wsh)[32] = (float(*)[32])(smem + 6144);
  const int gid = (blockIdx.x / 7) * 6 + (m - 1);
  const int row0 = gid * 32;
  if (row0 >= N_NODES) return;                       // 3126th tile is past 100000
  const int cg = t & 31;
  const int rg = (t >> 5) * 4;
  float acc[4][3] = {};
  for (int k0 = 0; k0 < 256; k0 += 64) {
#pragma unroll
    for (int i = 0; i < 8; i++) {
      int l = t + 256 * i;
      int r = l >> 6, kk = l & 63;
      xs[r][kk] = x[(size_t)(row0 + r) * F_INDIM + k0 + kk];
    }
#pragma unroll
    for (int i = 0; i < 8; i++) {
      int l = t + 256 * i;
      int kk = l >> 5, c = l & 31;
      wsz[kk][c] = Wz[(k0 + kk) * 32 + c];
      wsr[kk][c] = Wr[(k0 + kk) * 32 + c];
      wsh[kk][c] = Wh[(k0 + kk) * 32 + c];
    }
    __syncthreads();
#pragma unroll 4
    for (int kk = 0; kk < 64; kk++) {
      float wz = wsz[kk][cg], wr = wsr[kk][cg], wh = wsh[kk][cg];
#pragma unroll
      for (int r = 0; r < 4; r++) {
        float xv = xs[rg + r][kk];
        acc[r][0] = fmaf(xv, wz, acc[r][0]);
        acc[r][1] = fmaf(xv, wr, acc[r][1]);
        acc[r][2] = fmaf(xv, wh, acc[r][2]);
      }
    }
    __syncthreads();
  }
#pragma unroll
  for (int r = 0; r < 4; r++) {
    int row = row0 + rg + r;
#pragma unroll
    for (int g2 = 0; g2 < 3; g2++) {
      float other = __shfl_xor(acc[r][g2], 1);
      if ((cg & 1) == 0)
        XWb[(size_t)row * 48 + g2 * 16 + (cg >> 1)] = bf16pack(acc[r][g2], other);
    }
  }
}

// ---------------------------------------------------------------------------
// Per-bucket finalize (one block per coarse bucket):
//   LDS fine histogram (256 bins) + LDS float deg accumulation,
//   LDS scan -> rowstart/cnt/dis for the bucket's 256 nodes,
//   LDS cursor round permutes staged -> e2 (grouped by dst).
// Replaces: global scan, edge_place, deg_dis, dis_kernel.
// ---------------------------------------------------------------------------
__global__ __launch_bounds__(256) void finalize(
    const uint2* __restrict__ staged, const int* __restrict__ bucketCursor,
    uint2* __restrict__ e2, int* __restrict__ rowstart, int* __restrict__ cntA,
    float* __restrict__ dis) {
  __shared__ int fc[256];
  __shared__ float fd[256];
  __shared__ int fscan[256];
  __shared__ int fcur[256];
  const int t = threadIdx.x;
  const int b = blockIdx.x;
  const size_t lo = (size_t)b * BCAP;
  int M = bucketCursor[b]; if (M > BCAP) M = BCAP;
  fc[t] = 0; fd[t] = 0.f;
  __syncthreads();
  for (int i = t; i < M; i += 256) {
    uint2 ed = staged[lo + i];
    int fl = (ed.x >> 17) & 255;
    atomicAdd(&fc[fl], 1);
    atomicAdd(&fd[fl], __uint_as_float(ed.y));
  }
  __syncthreads();
  int v = fc[t];
  fscan[t] = v;
  __syncthreads();
  for (int off = 1; off < 256; off <<= 1) {
    int xv = (t >= off) ? fscan[t - off] : 0;
    __syncthreads();
    fscan[t] += xv;
    __syncthreads();
  }
  int excl = fscan[t] - v;
  int node = (b << 8) + t;
  if (node < N_NODES) {
    rowstart[node] = (int)lo + excl;
    cntA[node] = v;
    dis[node] = rsqrtf(fd[t] + 1.0f);
  }
  fcur[t] = excl;
  __syncthreads();
  for (int i = t; i < M; i += 256) {
    uint2 ed = staged[lo + i];
    int fl = (ed.x >> 17) & 255;
    int p = atomicAdd(&fcur[fl], 1);
    e2[lo + p] = make_uint2(ed.x & 0x1FFFFu, ed.y);
  }
}

// ---------------------------------------------------------------------------
// Fused gather + GRU + head. One wave64 per node. Gather: 5 edges per wave-
// load — lane l -> (slot s=l/12, quarter q=l%12), each lane loads dwordx4
// (8 bf16 feats) of its slot's src row. One shuffle pair per 5 edges.
// 8 f32 accumulators/lane; 5-slot reduce via per-wave LDS scratch.
// ---------------------------------------------------------------------------
#define FMA8(vv, nn)                                              \
  a0 = fmaf(nn, lo16(vv.x), a0); a1 = fmaf(nn, hi16(vv.x), a1);   \
  a2 = fmaf(nn, lo16(vv.y), a2); a3 = fmaf(nn, hi16(vv.y), a3);   \
  a4 = fmaf(nn, lo16(vv.z), a4); a5 = fmaf(nn, hi16(vv.z), a5);   \
  a6 = fmaf(nn, lo16(vv.w), a6); a7 = fmaf(nn, hi16(vv.w), a7);

__global__ __launch_bounds__(256, 6) void gru_gather(
    const uint2* __restrict__ e2, const int* __restrict__ rowstart,
    const int* __restrict__ cnt, const unsigned* __restrict__ XWb,
    const float* __restrict__ dis, const float* __restrict__ Hp,
    const float* __restrict__ bz, const float* __restrict__ br, const float* __restrict__ bh,
    const float* __restrict__ LzW, const float* __restrict__ Lzb,
    const float* __restrict__ LrW, const float* __restrict__ Lrb,
    const float* __restrict__ LhW, const float* __restrict__ Lhb,
    const float* __restrict__ hW, const float* __restrict__ hb,
    float* __restrict__ outY, float* __restrict__ outH, int N) {
  __shared__ unsigned sLz[1024], sLr[1024], sLh[1024];   // bf16-pair packed, 12 KB
  __shared__ float aggTmp[4][5][96];                     // per-wave slot partials
  __shared__ float sb96[96];
  __shared__ float sLzb[32], sLrb[32], sLhb[32], shW[32];
  __shared__ float2 sg2[4][48];
  __shared__ float shp[4][32], shr[4][32];
  __shared__ float shb;
  const int t = threadIdx.x;
  for (int i = t; i < 1024; i += 256) {
    int jj = i & 31, k2 = i >> 5;
    sLz[i] = bf16pack(LzW[(2 * k2) * 32 + jj], LzW[(2 * k2 + 1) * 32 + jj]);
    sLr[i] = bf16pack(LrW[(2 * k2) * 32 + jj], LrW[(2 * k2 + 1) * 32 + jj]);
    sLh[i] = bf16pack(LhW[(2 * k2) * 32 + jj], LhW[(2 * k2 + 1) * 32 + jj]);
  }
  if (t < 32) {
    sb96[t] = bz[t]; sb96[32 + t] = br[t]; sb96[64 + t] = bh[t];
    sLzb[t] = Lzb[t]; sLrb[t] = Lrb[t]; sLhb[t] = Lhb[t]; shW[t] = hW[t];
  }
  if (t == 0) shb = hb[0];
  __syncthreads();
  const int ws = t >> 6;
  const int l = t & 63;
  const int lp = (l < 48) ? l : 47;
  const int j = l & 31;
  const int half = l >> 5;
  const int sl = (l < 60) ? (l / 12) : 4;     // slot 0..4
  const int q  = (l < 60) ? (l % 12) : 11;    // dword-quad within row
  const float* sgf = (const float*)&sg2[ws][0];
  int wid = blockIdx.x * 4 + ws;
  int nw = gridDim.x * 4;
  for (int n = wid; n < N; n += nw) {
    const int start = rowstart[n];
    const int c = cnt[n];
    const float d = dis[n];
    float a0 = 0.f, a1 = 0.f, a2 = 0.f, a3 = 0.f;
    float a4 = 0.f, a5 = 0.f, a6 = 0.f, a7 = 0.f;
    for (int e0 = 0; e0 < c; e0 += 60) {
      int srcv = 0; float pw = 0.f;
      if (l < 60 && e0 + l < c) {
        uint2 ed = e2[start + e0 + l];
        srcv = (int)ed.x;
        pw = __uint_as_float(ed.y) * dis[srcv];      // w * dis[src]
      }
      int mm = c - e0; if (mm > 60) mm = 60;
      for (int k0 = 0; k0 < mm; k0 += 10) {          // 2 macro-iters: 10 edges
        int iA = k0 + sl, iB = k0 + 5 + sl;
        int sA = __shfl(srcv, iA), sB = __shfl(srcv, iB);
        float nA = __shfl(pw, iA), nB = __shfl(pw, iB);
        uint4 vA = *(const uint4*)(XWb + sA * 48 + (q << 2));
        uint4 vB = *(const uint4*)(XWb + sB * 48 + (q << 2));
        FMA8(vA, nA);
        FMA8(vB, nB);
      }
    }
    if (l < 60) {
      float4* dst4 = (float4*)&aggTmp[ws][sl][q * 8];
      dst4[0] = make_float4(a0, a1, a2, a3);
      dst4[1] = make_float4(a4, a5, a6, a7);
    }
    float g0 = 0.f, g1 = 0.f;
#pragma unroll
    for (int ss = 0; ss < 5; ss++) {
      float2 v2 = *(const float2*)&aggTmp[ws][ss][2 * lp];
      g0 += v2.x; g1 += v2.y;
    }
    g0 *= d; g1 *= d;                                // dis[dst] hoisted
    {   // self-loop + bias
      unsigned v = XWb[n * 48 + lp];
      float d2 = d * d;
      g0 = fmaf(d2, lo16(v), g0) + sb96[2 * lp];
      g1 = fmaf(d2, hi16(v), g1) + sb96[2 * lp + 1];
    }
    if (l < 48) sg2[ws][l] = make_float2(g0, g1);
    float hpj = 0.f;
    if (l < 32) { hpj = Hp[(size_t)n * 32 + l]; shp[ws][l] = hpj; }
    const unsigned* Wm = half ? sLr : sLz;
    const float* gsel = half ? (sgf + 32) : sgf;
    float val = half ? sLrb[j] : sLzb[j];
#pragma unroll
    for (int k2 = 0; k2 < 16; k2++) {
      unsigned wv = Wm[k2 * 32 + j];
      val = fmaf(gsel[2 * k2],     lo16(wv), val);
      val = fmaf(gsel[2 * k2 + 1], hi16(wv), val);
    }
#pragma unroll
    for (int k2 = 16; k2 < 32; k2++) {
      unsigned wv = Wm[k2 * 32 + j];
      val = fmaf(shp[ws][2 * k2 - 32], lo16(wv), val);
      val = fmaf(shp[ws][2 * k2 - 31], hi16(wv), val);
    }
    float gate = 1.f / (1.f + __expf(-val));
    if (half) shr[ws][j] = shp[ws][j] * gate;
    float s = half ? 0.f : sLhb[j];
#pragma unroll
    for (int k2 = 0; k2 < 16; k2++) {
      int kk2 = half ? (k2 + 16) : k2;
      unsigned wv = sLh[kk2 * 32 + j];
      float x0 = half ? shr[ws][2 * k2]     : sgf[64 + 2 * k2];
      float x1 = half ? shr[ws][2 * k2 + 1] : sgf[64 + 2 * k2 + 1];
      s = fmaf(x0, lo16(wv), s);
      s = fmaf(x1, hi16(wv), s);
    }
    s += __shfl_xor(s, 32);
    if (!half) {
      float ht = tanhf(s);
      float h = gate * hpj + (1.f - gate) * ht;
      outH[(size_t)n * 32 + j] = h;
      float cacc = fmaxf(h, 0.f) * shW[j];
#pragma unroll
      for (int off = 16; off > 0; off >>= 1) cacc += __shfl_xor(cacc, off, 32);
      if (j == 0) outY[n] = cacc + shb;
    }
  }
}

// ---------------------------------------------------------------------------
extern "C" void kernel_launch(void* const* d_in, const int* in_sizes, int n_in,
                              void* d_out, int out_size, void* d_ws, size_t ws_size,
                              hipStream_t stream) {
  const float* x    = (const float*)d_in[0];
  const int*   ei   = (const int*)d_in[1];
  const float* w    = (const float*)d_in[2];
  const float* Hp   = (const float*)d_in[3];
  const float* Wz   = (const float*)d_in[4];
  const float* bz   = (const float*)d_in[5];
  const float* Wr   = (const float*)d_in[6];
  const float* br   = (const float*)d_in[7];
  const float* Wh   = (const float*)d_in[8];
  const float* bh   = (const float*)d_in[9];
  const float* LzW  = (const float*)d_in[10];
  const float* Lzb  = (const float*)d_in[11];
  const float* LrW  = (const float*)d_in[12];
  const float* Lrb  = (const float*)d_in[13];
  const float* LhW  = (const float*)d_in[14];
  const float* Lhb  = (const float*)d_in[15];
  const float* hW   = (const float*)d_in[16];
  const float* hb   = (const float*)d_in[17];

  const int N = N_NODES;
  const int E = in_sizes[2];

  char* p = (char*)d_ws;
  unsigned* XWb   = (unsigned*)p;  p += (size_t)(N * 48 + 64) * 4;     // 19.2 MB
  uint2*    staged= (uint2*)p;     p += (size_t)NB * BCAP * 8;         // 28.8 MB
  uint2*    e2    = (uint2*)p;     p += (size_t)NB * BCAP * 8;         // 28.8 MB
  int* rowstart   = (int*)p;       p += (size_t)N * 4;
  int* cnt        = (int*)p;       p += (size_t)N * 4;
  float* dis      = (float*)p;     p += (size_t)N * 4;
  int* bucketCursor = (int*)p;     p += (NB + 1) * 4;

  float* outY = (float*)d_out;           // N
  float* outH = outY + N;                // N*32

  hipMemsetAsync(bucketCursor, 0, (NB + 1) * sizeof(int), stream);

  gemm_bin<<<K1_BLOCKS, 256, 0, stream>>>(x, Wz, Wr, Wh, XWb, ei, w,
                                          bucketCursor, staged, E);
  finalize<<<NB, 256, 0, stream>>>(staged, bucketCursor, e2, rowstart, cnt, dis);
  gru_gather<<<1536, 256, 0, stream>>>(e2, rowstart, cnt, XWb, dis, Hp,
                                       bz, br, bh,
                                       LzW, Lzb, LrW, Lrb, LhW, Lhb,
                                       hW, hb, outY, outH, N);
}

// Round 8
// 231.954 us; speedup vs baseline: 5.7599x; 1.2228x over previous
//
#include <hip/hip_runtime.h>
#include <math.h>

#define N_NODES 100000
#define F_INDIM 256
#define NB 391            // coarse buckets: dst>>8, ceil(100000/256)
#define BCAP 9216         // bucket capacity: mean 8192 edges + 11 sigma

// pack two f32 into bf16 pair (RNE), lo = a, hi = b
__device__ __forceinline__ unsigned bf16pack(float a, float b) {
  unsigned ua = __float_as_uint(a);
  ua += 0x7FFFu + ((ua >> 16) & 1u);
  unsigned ub = __float_as_uint(b);
  ub += 0x7FFFu + ((ub >> 16) & 1u);
  return (ub & 0xFFFF0000u) | (ua >> 16);
}
__device__ __forceinline__ float lo16(unsigned v) { return __uint_as_float(v << 16); }
__device__ __forceinline__ float hi16(unsigned v) { return __uint_as_float(v & 0xFFFF0000u); }

using bf16x8 = __attribute__((ext_vector_type(8))) short;
using f32x4  = __attribute__((ext_vector_type(4))) float;

// ---------------------------------------------------------------------------
// Heterogeneous (blockIdx%5: 0,1=bin 2,3,4=MFMA-GEMM), 512 threads.
// GEMM: XWb = x @ [Wz|Wr|Wh] via mfma_f32_16x16x32_bf16. 8 waves x 16 rows.
//   W staged bf16-transposed in LDS [96 cols][264 ushort] (pad 8 -> <=2-way
//   bank alias on ds_read_b128). A-frag: lane l = row l&15, k=(l>>4)*8+j,
//   loaded as 2x float4 from x and packed to bf16 in-register.
// Bin: block-aggregated coarse binning, ONE global atomic per (block,bin).
// ---------------------------------------------------------------------------
__global__ __launch_bounds__(512) void gemm_bin(
    const float* __restrict__ x,
    const float* __restrict__ Wz, const float* __restrict__ Wr, const float* __restrict__ Wh,
    unsigned* __restrict__ XWb,
    const int* __restrict__ ei, const float* __restrict__ w,
    int* __restrict__ bucketCursor, uint2* __restrict__ staged, int E) {
  __shared__ unsigned smem[12672];   // 50688 B, overlaid between roles
  const int t = threadIdx.x;
  const int m = blockIdx.x % 5;
  if (m < 2) {
    // ---- binning role ----
    int* lc    = (int*)smem;          // [NB] counts / rank cursors
    int* lbase = (int*)smem + 512;    // [NB] reserved base within bucket
    if (t < NB) lc[t] = 0;
    __syncthreads();
    const int bid = (blockIdx.x / 5) * 2 + m;
    const int base = bid * 6144;
#pragma unroll
    for (int i = 0; i < 12; i++) {
      int e = base + i * 512 + t;
      if (e < E) atomicAdd(&lc[((unsigned)ei[E + e]) >> 8], 1);
    }
    __syncthreads();
    if (t < NB) {
      int c = lc[t];
      lbase[t] = c ? atomicAdd(&bucketCursor[t], c) : 0;
    }
    __syncthreads();
    if (t < NB) lc[t] = 0;
    __syncthreads();
#pragma unroll
    for (int i = 0; i < 12; i++) {
      int e = base + i * 512 + t;
      if (e < E) {
        unsigned dst = (unsigned)ei[E + e];
        int b = dst >> 8;
        int r = lbase[b] + atomicAdd(&lc[b], 1);
        if (r < BCAP)
          staged[(size_t)b * BCAP + r] =
              make_uint2((unsigned)ei[e] | ((dst & 255u) << 17), __float_as_uint(w[e]));
      }
    }
    return;
  }
  // ---- MFMA GEMM role ----
  const int gid = (blockIdx.x / 5) * 3 + (m - 2);
  const int row0 = gid * 128;
  if (row0 >= N_NODES) return;
  ushort* sWt = (ushort*)smem;       // [96][264] bf16, col-major W (transposed)
  {
    const float* Ws[3] = {Wz, Wr, Wh};
#pragma unroll
    for (int mm = 0; mm < 3; mm++) {
      const float* Wp = Ws[mm];
      for (int i = t; i < 8192; i += 512) {
        int k = i >> 5, c = i & 31;
        unsigned uv = __float_as_uint(Wp[i]);
        uv += 0x7FFFu + ((uv >> 16) & 1u);
        sWt[(mm * 32 + c) * 264 + k] = (ushort)(uv >> 16);
      }
    }
  }
  __syncthreads();
  const int wv = t >> 6;       // wave 0..7
  const int l = t & 63;
  const int nl = l & 15;       // fragment row (A) / col (B,D)
  const int kg = l >> 4;       // k-group 0..3
  int arow = row0 + wv * 16 + nl;
  int arowc = arow < N_NODES ? arow : N_NODES - 1;   // clamp OOB loads (guarded on store)
  f32x4 acc[6];
#pragma unroll
  for (int c = 0; c < 6; c++) acc[c] = (f32x4){0.f, 0.f, 0.f, 0.f};
  const float* xrow = x + (size_t)arowc * F_INDIM + kg * 8;
#pragma unroll
  for (int ks = 0; ks < 8; ks++) {
    float4 xa = *(const float4*)(xrow + ks * 32);
    float4 xb = *(const float4*)(xrow + ks * 32 + 4);
    uint4 au;
    au.x = bf16pack(xa.x, xa.y);
    au.y = bf16pack(xa.z, xa.w);
    au.z = bf16pack(xb.x, xb.y);
    au.w = bf16pack(xb.z, xb.w);
    bf16x8 af = *(bf16x8*)&au;
#pragma unroll
    for (int c = 0; c < 6; c++) {
      const ushort* bp = sWt + (c * 16 + nl) * 264 + ks * 32 + kg * 8;
      bf16x8 bf = *(const bf16x8*)bp;
      acc[c] = __builtin_amdgcn_mfma_f32_16x16x32_bf16(af, bf, acc[c], 0, 0, 0);
    }
  }
  // D layout: lane holds col n=nl, rows kg*4+r. Pack col pairs via shfl_xor(1).
#pragma unroll
  for (int c = 0; c < 6; c++) {
#pragma unroll
    for (int r = 0; r < 4; r++) {
      float v = acc[c][r];
      float o = __shfl_xor(v, 1);
      int orow = row0 + wv * 16 + kg * 4 + r;
      if ((nl & 1) == 0 && orow < N_NODES)
        XWb[(size_t)orow * 48 + c * 8 + (nl >> 1)] = bf16pack(v, o);
    }
  }
}

// ---------------------------------------------------------------------------
// Per-bucket finalize (one block per coarse bucket):
//   LDS fine histogram (256 bins) + LDS float deg accumulation,
//   LDS scan -> rowstart/cnt/dis, LDS cursor round permutes staged -> e2.
// ---------------------------------------------------------------------------
__global__ __launch_bounds__(256) void finalize(
    const uint2* __restrict__ staged, const int* __restrict__ bucketCursor,
    uint2* __restrict__ e2, int* __restrict__ rowstart, int* __restrict__ cntA,
    float* __restrict__ dis) {
  __shared__ int fc[256];
  __shared__ float fd[256];
  __shared__ int fscan[256];
  __shared__ int fcur[256];
  const int t = threadIdx.x;
  const int b = blockIdx.x;
  const size_t lo = (size_t)b * BCAP;
  int M = bucketCursor[b]; if (M > BCAP) M = BCAP;
  fc[t] = 0; fd[t] = 0.f;
  __syncthreads();
  for (int i = t; i < M; i += 256) {
    uint2 ed = staged[lo + i];
    int fl = (ed.x >> 17) & 255;
    atomicAdd(&fc[fl], 1);
    atomicAdd(&fd[fl], __uint_as_float(ed.y));
  }
  __syncthreads();
  int v = fc[t];
  fscan[t] = v;
  __syncthreads();
  for (int off = 1; off < 256; off <<= 1) {
    int xv = (t >= off) ? fscan[t - off] : 0;
    __syncthreads();
    fscan[t] += xv;
    __syncthreads();
  }
  int excl = fscan[t] - v;
  int node = (b << 8) + t;
  if (node < N_NODES) {
    rowstart[node] = (int)lo + excl;
    cntA[node] = v;
    dis[node] = rsqrtf(fd[t] + 1.0f);
  }
  fcur[t] = excl;
  __syncthreads();
  for (int i = t; i < M; i += 256) {
    uint2 ed = staged[lo + i];
    int fl = (ed.x >> 17) & 255;
    int p = atomicAdd(&fcur[fl], 1);
    e2[lo + p] = make_uint2(ed.x & 0x1FFFFu, ed.y);
  }
}

// ---------------------------------------------------------------------------
// Fused gather + GRU + head. One wave64 per node. Gather: 5 edges per wave-
// load — lane l -> (slot s=l/12, quarter q=l%12), each lane loads dwordx4
// (8 bf16 feats) of its slot's src row. One shuffle pair per 5 edges.
// ---------------------------------------------------------------------------
#define FMA8(vv, nn)                                              \
  a0 = fmaf(nn, lo16(vv.x), a0); a1 = fmaf(nn, hi16(vv.x), a1);   \
  a2 = fmaf(nn, lo16(vv.y), a2); a3 = fmaf(nn, hi16(vv.y), a3);   \
  a4 = fmaf(nn, lo16(vv.z), a4); a5 = fmaf(nn, hi16(vv.z), a5);   \
  a6 = fmaf(nn, lo16(vv.w), a6); a7 = fmaf(nn, hi16(vv.w), a7);

__global__ __launch_bounds__(256, 6) void gru_gather(
    const uint2* __restrict__ e2, const int* __restrict__ rowstart,
    const int* __restrict__ cnt, const unsigned* __restrict__ XWb,
    const float* __restrict__ dis, const float* __restrict__ Hp,
    const float* __restrict__ bz, const float* __restrict__ br, const float* __restrict__ bh,
    const float* __restrict__ LzW, const float* __restrict__ Lzb,
    const float* __restrict__ LrW, const float* __restrict__ Lrb,
    const float* __restrict__ LhW, const float* __restrict__ Lhb,
    const float* __restrict__ hW, const float* __restrict__ hb,
    float* __restrict__ outY, float* __restrict__ outH, int N) {
  __shared__ unsigned sLz[1024], sLr[1024], sLh[1024];   // bf16-pair packed, 12 KB
  __shared__ float aggTmp[4][5][96];
  __shared__ float sb96[96];
  __shared__ float sLzb[32], sLrb[32], sLhb[32], shW[32];
  __shared__ float2 sg2[4][48];
  __shared__ float shp[4][32], shr[4][32];
  __shared__ float shb;
  const int t = threadIdx.x;
  for (int i = t; i < 1024; i += 256) {
    int jj = i & 31, k2 = i >> 5;
    sLz[i] = bf16pack(LzW[(2 * k2) * 32 + jj], LzW[(2 * k2 + 1) * 32 + jj]);
    sLr[i] = bf16pack(LrW[(2 * k2) * 32 + jj], LrW[(2 * k2 + 1) * 32 + jj]);
    sLh[i] = bf16pack(LhW[(2 * k2) * 32 + jj], LhW[(2 * k2 + 1) * 32 + jj]);
  }
  if (t < 32) {
    sb96[t] = bz[t]; sb96[32 + t] = br[t]; sb96[64 + t] = bh[t];
    sLzb[t] = Lzb[t]; sLrb[t] = Lrb[t]; sLhb[t] = Lhb[t]; shW[t] = hW[t];
  }
  if (t == 0) shb = hb[0];
  __syncthreads();
  const int ws = t >> 6;
  const int l = t & 63;
  const int lp = (l < 48) ? l : 47;
  const int j = l & 31;
  const int half = l >> 5;
  const int sl = (l < 60) ? (l / 12) : 4;
  const int q  = (l < 60) ? (l % 12) : 11;
  const float* sgf = (const float*)&sg2[ws][0];
  int wid = blockIdx.x * 4 + ws;
  int nw = gridDim.x * 4;
  for (int n = wid; n < N; n += nw) {
    const int start = rowstart[n];
    const int c = cnt[n];
    const float d = dis[n];
    float a0 = 0.f, a1 = 0.f, a2 = 0.f, a3 = 0.f;
    float a4 = 0.f, a5 = 0.f, a6 = 0.f, a7 = 0.f;
    for (int e0 = 0; e0 < c; e0 += 60) {
      int srcv = 0; float pw = 0.f;
      if (l < 60 && e0 + l < c) {
        uint2 ed = e2[start + e0 + l];
        srcv = (int)ed.x;
        pw = __uint_as_float(ed.y) * dis[srcv];      // w * dis[src]
      }
      int mm = c - e0; if (mm > 60) mm = 60;
      for (int k0 = 0; k0 < mm; k0 += 10) {          // 2 macro-iters: 10 edges
        int iA = k0 + sl, iB = k0 + 5 + sl;
        int sA = __shfl(srcv, iA), sB = __shfl(srcv, iB);
        float nA = __shfl(pw, iA), nB = __shfl(pw, iB);
        uint4 vA = *(const uint4*)(XWb + sA * 48 + (q << 2));
        uint4 vB = *(const uint4*)(XWb + sB * 48 + (q << 2));
        FMA8(vA, nA);
        FMA8(vB, nB);
      }
    }
    if (l < 60) {
      float4* dst4 = (float4*)&aggTmp[ws][sl][q * 8];
      dst4[0] = make_float4(a0, a1, a2, a3);
      dst4[1] = make_float4(a4, a5, a6, a7);
    }
    float g0 = 0.f, g1 = 0.f;
#pragma unroll
    for (int ss = 0; ss < 5; ss++) {
      float2 v2 = *(const float2*)&aggTmp[ws][ss][2 * lp];
      g0 += v2.x; g1 += v2.y;
    }
    g0 *= d; g1 *= d;
    {   // self-loop + bias
      unsigned v = XWb[n * 48 + lp];
      float d2 = d * d;
      g0 = fmaf(d2, lo16(v), g0) + sb96[2 * lp];
      g1 = fmaf(d2, hi16(v), g1) + sb96[2 * lp + 1];
    }
    if (l < 48) sg2[ws][l] = make_float2(g0, g1);
    float hpj = 0.f;
    if (l < 32) { hpj = Hp[(size_t)n * 32 + l]; shp[ws][l] = hpj; }
    const unsigned* Wm = half ? sLr : sLz;
    const float* gsel = half ? (sgf + 32) : sgf;
    float val = half ? sLrb[j] : sLzb[j];
#pragma unroll
    for (int k2 = 0; k2 < 16; k2++) {
      unsigned wv = Wm[k2 * 32 + j];
      val = fmaf(gsel[2 * k2],     lo16(wv), val);
      val = fmaf(gsel[2 * k2 + 1], hi16(wv), val);
    }
#pragma unroll
    for (int k2 = 16; k2 < 32; k2++) {
      unsigned wv = Wm[k2 * 32 + j];
      val = fmaf(shp[ws][2 * k2 - 32], lo16(wv), val);
      val = fmaf(shp[ws][2 * k2 - 31], hi16(wv), val);
    }
    float gate = 1.f / (1.f + __expf(-val));
    if (half) shr[ws][j] = shp[ws][j] * gate;
    float s = half ? 0.f : sLhb[j];
#pragma unroll
    for (int k2 = 0; k2 < 16; k2++) {
      int kk2 = half ? (k2 + 16) : k2;
      unsigned wv = sLh[kk2 * 32 + j];
      float x0 = half ? shr[ws][2 * k2]     : sgf[64 + 2 * k2];
      float x1 = half ? shr[ws][2 * k2 + 1] : sgf[64 + 2 * k2 + 1];
      s = fmaf(x0, lo16(wv), s);
      s = fmaf(x1, hi16(wv), s);
    }
    s += __shfl_xor(s, 32);
    if (!half) {
      float ht = tanhf(s);
      float h = gate * hpj + (1.f - gate) * ht;
      outH[(size_t)n * 32 + j] = h;
      float cacc = fmaxf(h, 0.f) * shW[j];
#pragma unroll
      for (int off = 16; off > 0; off >>= 1) cacc += __shfl_xor(cacc, off, 32);
      if (j == 0) outY[n] = cacc + shb;
    }
  }
}

// ---------------------------------------------------------------------------
extern "C" void kernel_launch(void* const* d_in, const int* in_sizes, int n_in,
                              void* d_out, int out_size, void* d_ws, size_t ws_size,
                              hipStream_t stream) {
  const float* x    = (const float*)d_in[0];
  const int*   ei   = (const int*)d_in[1];
  const float* w    = (const float*)d_in[2];
  const float* Hp   = (const float*)d_in[3];
  const float* Wz   = (const float*)d_in[4];
  const float* bz   = (const float*)d_in[5];
  const float* Wr   = (const float*)d_in[6];
  const float* br   = (const float*)d_in[7];
  const float* Wh   = (const float*)d_in[8];
  const float* bh   = (const float*)d_in[9];
  const float* LzW  = (const float*)d_in[10];
  const float* Lzb  = (const float*)d_in[11];
  const float* LrW  = (const float*)d_in[12];
  const float* Lrb  = (const float*)d_in[13];
  const float* LhW  = (const float*)d_in[14];
  const float* Lhb  = (const float*)d_in[15];
  const float* hW   = (const float*)d_in[16];
  const float* hb   = (const float*)d_in[17];

  const int N = N_NODES;
  const int E = in_sizes[2];

  char* p = (char*)d_ws;
  unsigned* XWb   = (unsigned*)p;  p += (size_t)(N * 48 + 64) * 4;     // 19.2 MB
  uint2*    staged= (uint2*)p;     p += (size_t)NB * BCAP * 8;         // 28.8 MB
  uint2*    e2    = (uint2*)p;     p += (size_t)NB * BCAP * 8;         // 28.8 MB
  int* rowstart   = (int*)p;       p += (size_t)N * 4;
  int* cnt        = (int*)p;       p += (size_t)N * 4;
  float* dis      = (float*)p;     p += (size_t)N * 4;
  int* bucketCursor = (int*)p;     p += (NB + 1) * 4;

  float* outY = (float*)d_out;           // N
  float* outH = outY + N;                // N*32

  hipMemsetAsync(bucketCursor, 0, (NB + 1) * sizeof(int), stream);

  // 261 groups of 5: 522 bin blocks (last guarded), 783 gemm blocks (last guarded)
  gemm_bin<<<1305, 512, 0, stream>>>(x, Wz, Wr, Wh, XWb, ei, w,
                                     bucketCursor, staged, E);
  finalize<<<NB, 256, 0, stream>>>(staged, bucketCursor, e2, rowstart, cnt, dis);
  gru_gather<<<1536, 256, 0, stream>>>(e2, rowstart, cnt, XWb, dis, Hp,
                                       bz, br, bh,
                                       LzW, Lzb, LrW, Lrb, LhW, Lhb,
                                       hW, hb, outY, outH, N);
}